// Round 9
// baseline (1184.782 us; speedup 1.0000x reference)
//
#include <hip/hip_runtime.h>
#include <hip/hip_bf16.h>

// AtomicScaleModule — CGCNN GNN forward, MFMA split-bf16 (~f32 accuracy).
// 4 groups (64 atoms) per wave; no fences; two-phase [32][69] slab.
// S buffer eliminated: s = a@MW1[:64]+b1 recomputed in consumer; the A
// fragments built for s are HELD and reused for U1, and the residual is
// reconstructed from hi+lo (error ~2^-17) -> A is read exactly once/dense.
// All kernels at (256,2): R8's (256,3) forced VGPR caps -> spills -> +54%.
//   a = X@AE + ae_b
//   per layer: t = a@MW1[64:128]                        (produced upstream)
//              s = a@MW1[0:64]+b1                       (in consumer)
//              H = sum_c relu(s + t[idx])               (gather)
//              agg = H@MW2 + 12*b2
//              u1 = relu(a@UW1[0:64] + agg@UW1[64:128] + ub1)
//              a' = relu(a + u1@UW2 + ub2)  (+ fused t of next layer)
//   af = relu(a@FX1+fb1)@FX2+fb2 ; props = af@PW^T+pb   (fused into last dense)
// T double-buffered across layers. nbr_fea / ne_w / ne_b dead.

constexpr int NA = 300000;

typedef short  s16x8 __attribute__((ext_vector_type(8)));
typedef float  f32x4 __attribute__((ext_vector_type(4)));

#define DEVFN static __device__ __forceinline__

DEVFN unsigned short f2bf(float x) {
  unsigned u = __float_as_uint(x);
  u += 0x7fffu + ((u >> 16) & 1u);          // RTNE
  return (unsigned short)(u >> 16);
}
DEVFN float bf2f(unsigned short h) { return __uint_as_float(((unsigned)h) << 16); }

// split x -> hi + lo bf16 pair (v_cvt_pk_bf16_f32-friendly)
DEVFN void mk_frag(const float* v, s16x8& hi, s16x8& lo) {
#pragma unroll
  for (int i = 0; i < 8; i += 2) {
    __hip_bfloat162 h2 = __float22bfloat162_rn(make_float2(v[i], v[i + 1]));
    float2 hf = __bfloat1622float2(h2);
    __hip_bfloat162 l2 = __float22bfloat162_rn(make_float2(v[i] - hf.x, v[i + 1] - hf.y));
    hi[i]     = (short)__bfloat16_as_ushort(h2.x);
    hi[i + 1] = (short)__bfloat16_as_ushort(h2.y);
    lo[i]     = (short)__bfloat16_as_ushort(l2.x);
    lo[i + 1] = (short)__bfloat16_as_ushort(l2.y);
  }
}

DEVFN f32x4 mf3(s16x8 ah, s16x8 al, s16x8 bh, s16x8 bl, f32x4 c) {
  c = __builtin_amdgcn_mfma_f32_16x16x32_bf16(al, bh, c, 0, 0, 0);
  c = __builtin_amdgcn_mfma_f32_16x16x32_bf16(ah, bl, c, 0, 0, 0);
  c = __builtin_amdgcn_mfma_f32_16x16x32_bf16(ah, bh, c, 0, 0, 0);
  return c;
}

DEVFN void ldB(const unsigned short* __restrict__ WH, const unsigned short* __restrict__ WL,
               int seg, int kt, int ct, int CT, int l, s16x8& bh, s16x8& bl) {
  size_t o = (size_t)seg + ((size_t)((kt * CT + ct) * 64 + l)) * 8;
  bh = *(const s16x8*)(WH + o);
  bl = *(const s16x8*)(WL + o);
}

DEVFN f32x4 bias4(float bv) { f32x4 c; c[0] = bv; c[1] = bv; c[2] = bv; c[3] = bv; return c; }

// one 64x64 GEMM stage for all 4 groups: 8 B-pairs, 96 MFMA.
DEVFN void stage_mm(const unsigned short* __restrict__ WH,
                    const unsigned short* __restrict__ WL,
                    int seg, int kt0,
                    const s16x8 (&fh)[4][2], const s16x8 (&fl)[4][2],
                    int l, f32x4 (&cc)[4][4]) {
#pragma unroll
  for (int ct = 0; ct < 4; ++ct)
#pragma unroll
    for (int kt = 0; kt < 2; ++kt) {
      s16x8 bh, bl; ldB(WH, WL, seg, kt0 + kt, ct, 4, l, bh, bl);
#pragma unroll
      for (int gr = 0; gr < 4; ++gr)
        cc[gr][ct] = mf3(fh[gr][kt], fl[gr][kt], bh, bl, cc[gr][ct]);
    }
}

// build A-fragments for all 4 groups from a global f32 [NA][64] matrix
DEVFN void frags_from_global(const float* __restrict__ A, const int (&nat)[4],
                             int g, s16x8 (&fh)[4][2], s16x8 (&fl)[4][2]) {
#pragma unroll
  for (int gr = 0; gr < 4; ++gr)
#pragma unroll
    for (int kt = 0; kt < 2; ++kt) {
      const float* p8 = A + (size_t)nat[gr] * 64 + kt * 32 + g * 8;
      f32x4 a = *(const f32x4*)p8;
      f32x4 b = *(const f32x4*)(p8 + 4);
      float v[8] = {a[0], a[1], a[2], a[3], b[0], b[1], b[2], b[3]};
      mk_frag(v, fh[gr][kt], fl[gr][kt]);
    }
}

// ---- two-phase slab transpose: half h covers features 32h..32h+31 ---------
DEVFN void put_half(float (*sl)[69], int m, int g, const f32x4 (&cc)[4][4], int h) {
#pragma unroll
  for (int gr = 0; gr < 4; ++gr)
#pragma unroll
    for (int c = 0; c < 2; ++c)
#pragma unroll
      for (int r = 0; r < 4; ++r)
        sl[16 * c + m][gr * 17 + 4 * g + r] = cc[gr][2 * h + c][r];
}
DEVFN void get_half(const float (*sl)[69], int m, int g, int gr, float* v) {
#pragma unroll
  for (int i = 0; i < 8; ++i) v[i] = sl[8 * g + i][gr * 17 + m];
}

DEVFN void trans_frags(float (*sl)[69], int m, int g, const f32x4 (&cc)[4][4],
                       s16x8 (&fh)[4][2], s16x8 (&fl)[4][2]) {
#pragma unroll
  for (int h = 0; h < 2; ++h) {
    put_half(sl, m, g, cc, h);
#pragma unroll
    for (int gr = 0; gr < 4; ++gr) {
      float v[8];
      get_half(sl, m, g, gr, v);
      mk_frag(v, fh[gr][h], fl[gr][h]);
    }
  }
}

DEVFN void trans_store_T(float (*sl)[69], int m, int g, const f32x4 (&cc)[4][4],
                         unsigned short* __restrict__ B, const int (&nat)[4], const bool (&ok)[4]) {
#pragma unroll
  for (int h = 0; h < 2; ++h) {
    put_half(sl, m, g, cc, h);
#pragma unroll
    for (int gr = 0; gr < 4; ++gr) {
      float v[8];
      get_half(sl, m, g, gr, v);
      if (ok[gr]) {
        uint4 q;
        unsigned* qp = (unsigned*)&q;
#pragma unroll
        for (int p = 0; p < 4; ++p)
          qp[p] = (unsigned)f2bf(v[2 * p]) | ((unsigned)f2bf(v[2 * p + 1]) << 16);
        *(uint4*)(B + (size_t)nat[gr] * 64 + 32 * h + 8 * g) = q;
      }
    }
  }
}

// ---- weight pre-conversion to B-frag layout (hi/lo bf16) ------------------
// Segments (entry offsets): AE 0 (96x64); per layer base=6144+l*24576:
//   MW1 +0 (128x64), MW2 +8192 (64x64), UW1 +12288 (128x64), UW2 +20480 (64x64)
// FX1 79872 (64x128), FX2 88064 (128x64). Total 96256 entries.
__global__ __launch_bounds__(256) void k_prep(
    const float* __restrict__ ae, const float* __restrict__ mw1,
    const float* __restrict__ mw2, const float* __restrict__ uw1,
    const float* __restrict__ uw2, const float* __restrict__ fx1,
    const float* __restrict__ fx2,
    unsigned short* __restrict__ WH, unsigned short* __restrict__ WL) {
  int e = blockIdx.x * 256 + threadIdx.x;
  const float* src;
  int K, N, loc;
  if (e < 6144) { src = ae; K = 92; N = 64; loc = e; }
  else if (e < 79872) {
    int r = e - 6144;
    int lyr = r / 24576, q = r % 24576;
    size_t l64 = (size_t)lyr * 64;
    if (q < 8192)       { src = mw1 + l64 * 128; K = 128; N = 64; loc = q; }
    else if (q < 12288) { src = mw2 + l64 * 64;  K = 64;  N = 64; loc = q - 8192; }
    else if (q < 20480) { src = uw1 + l64 * 128; K = 128; N = 64; loc = q - 12288; }
    else                { src = uw2 + l64 * 64;  K = 64;  N = 64; loc = q - 20480; }
  }
  else if (e < 88064) { src = fx1; K = 64;  N = 128; loc = e - 79872; }
  else if (e < 96256) { src = fx2; K = 128; N = 64;  loc = e - 88064; }
  else return;
  int k = (N == 64) ? (loc >> 6) : (loc >> 7);
  int j = loc & (N - 1);
  float v = (k < K) ? src[(size_t)k * N + j] : 0.f;
  unsigned short h = f2bf(v);
  int CT = N >> 4;
  int lane = ((k >> 3) & 3) * 16 + (j & 15);
  int fidx = (e - loc) + (((k >> 5) * CT + (j >> 4)) * 64 + lane) * 8 + (k & 7);
  WH[fidx] = h;
  WL[fidx] = f2bf(v - bf2f(h));
}

// ---- embed + t of layer 0 (64 atoms per wave) -----------------------------
__global__ __launch_bounds__(256, 2) void k_embed_t(
    const float* __restrict__ X,
    const unsigned short* __restrict__ WH, const unsigned short* __restrict__ WL,
    const float* __restrict__ aeb,
    float* __restrict__ A0, unsigned short* __restrict__ T) {
  __shared__ float slab[4][32][69];
  int w = threadIdx.x >> 6, l = threadIdx.x & 63, m = l & 15, g = l >> 4;
  float (*sl)[69] = slab[w];
  int nbase = blockIdx.x * 256 + w * 64;
  int nat[4]; bool ok[4];
#pragma unroll
  for (int gr = 0; gr < 4; ++gr) {
    nat[gr] = nbase + gr * 16 + m;
    ok[gr] = nat[gr] < NA;
    if (!ok[gr]) nat[gr] = NA - 1;
  }

  // a0 = X@AE + ae_b ; X fragments built per kt to bound liveness
  f32x4 ca[4][4];
#pragma unroll
  for (int gr = 0; gr < 4; ++gr)
#pragma unroll
    for (int ct = 0; ct < 4; ++ct) ca[gr][ct] = bias4(aeb[16 * ct + m]);
#pragma unroll
  for (int kt = 0; kt < 3; ++kt) {
    s16x8 xh[4], xl[4];
#pragma unroll
    for (int gr = 0; gr < 4; ++gr) {
      const float* xr = X + (size_t)nat[gr] * 92;
      float v[8];
      if (kt < 2) {
        f32x4 a = *(const f32x4*)(xr + kt * 32 + g * 8);
        f32x4 b = *(const f32x4*)(xr + kt * 32 + g * 8 + 4);
        v[0]=a[0]; v[1]=a[1]; v[2]=a[2]; v[3]=a[3]; v[4]=b[0]; v[5]=b[1]; v[6]=b[2]; v[7]=b[3];
      } else if (g < 3) {
        f32x4 a = *(const f32x4*)(xr + 64 + g * 8);
        f32x4 b = *(const f32x4*)(xr + 64 + g * 8 + 4);
        v[0]=a[0]; v[1]=a[1]; v[2]=a[2]; v[3]=a[3]; v[4]=b[0]; v[5]=b[1]; v[6]=b[2]; v[7]=b[3];
      } else {
        f32x4 a = *(const f32x4*)(xr + 88);   // 88..91 valid, 92..95 pad
        v[0]=a[0]; v[1]=a[1]; v[2]=a[2]; v[3]=a[3]; v[4]=0.f; v[5]=0.f; v[6]=0.f; v[7]=0.f;
      }
      mk_frag(v, xh[gr], xl[gr]);
    }
#pragma unroll
    for (int ct = 0; ct < 4; ++ct) {
      s16x8 bh, bl; ldB(WH, WL, 0, kt, ct, 4, l, bh, bl);
#pragma unroll
      for (int gr = 0; gr < 4; ++gr)
        ca[gr][ct] = mf3(xh[gr], xl[gr], bh, bl, ca[gr][ct]);
    }
  }

  // transpose a0: store A0 coalesced + build fragments, one read pass
  s16x8 ah[4][2], al[4][2];
#pragma unroll
  for (int h = 0; h < 2; ++h) {
    put_half(sl, m, g, ca, h);
#pragma unroll
    for (int gr = 0; gr < 4; ++gr) {
      float v[8];
      get_half(sl, m, g, gr, v);
      if (ok[gr]) {
        float* p = A0 + (size_t)nat[gr] * 64 + 32 * h + 8 * g;
        *(float4*)p = make_float4(v[0], v[1], v[2], v[3]);
        *(float4*)(p + 4) = make_float4(v[4], v[5], v[6], v[7]);
      }
      mk_frag(v, ah[gr][h], al[gr][h]);
    }
  }

  // t0 = a0@MW1_0[64:128]
  f32x4 cT[4][4];
#pragma unroll
  for (int gr = 0; gr < 4; ++gr)
#pragma unroll
    for (int ct = 0; ct < 4; ++ct) cT[gr][ct] = bias4(0.f);
  stage_mm(WH, WL, 6144, 2, ah, al, l, cT);
  trans_store_T(sl, m, g, cT, T, nat, ok);
}

// ---- fused: s + gather + dense chain (+ next-layer t | + fx tail) ---------
template <int HAS_NEXT, int HAS_FX>
__global__ __launch_bounds__(256, 2) void k_dense(
    const float* __restrict__ A,
    const unsigned short* __restrict__ T, const int* __restrict__ IDX,
    const unsigned short* __restrict__ WH, const unsigned short* __restrict__ WL,
    int segS, int segW2, int segU1, int segU2, int segWn,
    const float* __restrict__ b1, const float* __restrict__ b2,
    const float* __restrict__ ub1, const float* __restrict__ ub2,
    const float* __restrict__ fb1, const float* __restrict__ fb2,
    const float* __restrict__ PW, const float* __restrict__ PB,
    float* __restrict__ Anew, unsigned short* __restrict__ Tout,
    float* __restrict__ AF, float* __restrict__ PR) {
  __shared__ float slab[4][32][69];
  int w = threadIdx.x >> 6, l = threadIdx.x & 63, m = l & 15, g = l >> 4;
  float (*sl)[69] = slab[w];
  int nbase = blockIdx.x * 256 + w * 64;
  int nat[4]; bool ok[4];
#pragma unroll
  for (int gr = 0; gr < 4; ++gr) {
    nat[gr] = nbase + gr * 16 + m;
    ok[gr] = nat[gr] < NA;
    if (!ok[gr]) nat[gr] = NA - 1;
  }

  // A fragments: built ONCE, reused for s-stage, U1-stage, and residual.
  s16x8 arh[4][2], arl[4][2];
  frags_from_global(A, nat, g, arh, arl);

  // s = a@MW1[0:64] + b1
  f32x4 cs[4][4];
#pragma unroll
  for (int gr = 0; gr < 4; ++gr)
#pragma unroll
    for (int ct = 0; ct < 4; ++ct) cs[gr][ct] = bias4(b1[16 * ct + m]);
  stage_mm(WH, WL, segS, 0, arh, arl, l, cs);

  // gather: H = sum_c relu(s + t[idx]); s via slab transpose, per half.
  s16x8 hh[4][2], hl[4][2];
#pragma unroll
  for (int h = 0; h < 2; ++h) {
    put_half(sl, m, g, cs, h);
#pragma unroll
    for (int gr = 0; gr < 4; ++gr) {
      float sv[8];
      get_half(sl, m, g, gr, sv);
      const int* ip = IDX + (size_t)nat[gr] * 12;
      int4 i0 = *(const int4*)ip;
      int4 i1 = *(const int4*)(ip + 4);
      int4 i2 = *(const int4*)(ip + 8);
      int idxs[12] = {i0.x, i0.y, i0.z, i0.w, i1.x, i1.y, i1.z, i1.w,
                      i2.x, i2.y, i2.z, i2.w};
      int f0 = 32 * h + 8 * g;
      float ha[8] = {0, 0, 0, 0, 0, 0, 0, 0};
#pragma unroll
      for (int c = 0; c < 12; ++c) {
        uint4 tv = *(const uint4*)(T + (size_t)idxs[c] * 64 + f0);
        ha[0] += fmaxf(sv[0] + bf2f((unsigned short)(tv.x & 0xffff)), 0.f);
        ha[1] += fmaxf(sv[1] + bf2f((unsigned short)(tv.x >> 16)), 0.f);
        ha[2] += fmaxf(sv[2] + bf2f((unsigned short)(tv.y & 0xffff)), 0.f);
        ha[3] += fmaxf(sv[3] + bf2f((unsigned short)(tv.y >> 16)), 0.f);
        ha[4] += fmaxf(sv[4] + bf2f((unsigned short)(tv.z & 0xffff)), 0.f);
        ha[5] += fmaxf(sv[5] + bf2f((unsigned short)(tv.z >> 16)), 0.f);
        ha[6] += fmaxf(sv[6] + bf2f((unsigned short)(tv.w & 0xffff)), 0.f);
        ha[7] += fmaxf(sv[7] + bf2f((unsigned short)(tv.w >> 16)), 0.f);
      }
      mk_frag(ha, hh[gr][h], hl[gr][h]);
    }
  }

  // agg = H@W2 + 12*b2
  f32x4 cg[4][4];
#pragma unroll
  for (int gr = 0; gr < 4; ++gr)
#pragma unroll
    for (int ct = 0; ct < 4; ++ct) cg[gr][ct] = bias4(12.f * b2[16 * ct + m]);
  stage_mm(WH, WL, segW2, 0, hh, hl, l, cg);

  // u1 = relu(a@U1[0:64] + agg@U1[64:128] + ub1); reuses held A fragments
  f32x4 cu[4][4];
#pragma unroll
  for (int gr = 0; gr < 4; ++gr)
#pragma unroll
    for (int ct = 0; ct < 4; ++ct) cu[gr][ct] = bias4(ub1[16 * ct + m]);
  stage_mm(WH, WL, segU1, 0, arh, arl, l, cu);
  {
    s16x8 qh[4][2], ql[4][2];
    trans_frags(sl, m, g, cg, qh, ql);
    stage_mm(WH, WL, segU1, 2, qh, ql, l, cu);
  }
#pragma unroll
  for (int gr = 0; gr < 4; ++gr)
#pragma unroll
    for (int ct = 0; ct < 4; ++ct)
#pragma unroll
      for (int r = 0; r < 4; ++r) cu[gr][ct][r] = fmaxf(cu[gr][ct][r], 0.f);

  // upd = u1@U2 + ub2
  f32x4 cd[4][4];
#pragma unroll
  for (int gr = 0; gr < 4; ++gr)
#pragma unroll
    for (int ct = 0; ct < 4; ++ct) cd[gr][ct] = bias4(ub2[16 * ct + m]);
  {
    s16x8 uh[4][2], ul[4][2];
    trans_frags(sl, m, g, cu, uh, ul);
    stage_mm(WH, WL, segU2, 0, uh, ul, l, cd);
  }

  // a' = relu(a + upd): residual reconstructed from held frags (hi+lo),
  // coalesced store, fragments for next stages — one pass, NO A re-read.
  s16x8 anh[4][2], anl[4][2];
#pragma unroll
  for (int h = 0; h < 2; ++h) {
    put_half(sl, m, g, cd, h);
#pragma unroll
    for (int gr = 0; gr < 4; ++gr) {
      float v[8];
      get_half(sl, m, g, gr, v);
#pragma unroll
      for (int i = 0; i < 8; ++i) {
        float av = bf2f((unsigned short)arh[gr][h][i]) + bf2f((unsigned short)arl[gr][h][i]);
        v[i] = fmaxf(v[i] + av, 0.f);
      }
      if (ok[gr]) {
        float* p = Anew + (size_t)nat[gr] * 64 + 32 * h + 8 * g;
        *(float4*)p = make_float4(v[0], v[1], v[2], v[3]);
        *(float4*)(p + 4) = make_float4(v[4], v[5], v[6], v[7]);
      }
      if constexpr (HAS_NEXT || HAS_FX) mk_frag(v, anh[gr][h], anl[gr][h]);
    }
  }

  if constexpr (HAS_NEXT) {
    // t_next = a'@MW1_next[64:128]
    f32x4 cT[4][4];
#pragma unroll
    for (int gr = 0; gr < 4; ++gr)
#pragma unroll
      for (int ct = 0; ct < 4; ++ct) cT[gr][ct] = bias4(0.f);
    stage_mm(WH, WL, segWn, 2, anh, anl, l, cT);
    trans_store_T(sl, m, g, cT, Tout, nat, ok);
  }

  if constexpr (HAS_FX) {
    // af = relu(raw@FX1+fb1)@FX2+fb2, hidden 128 in two 64-col rounds
    f32x4 cf[4][4];
#pragma unroll
    for (int gr = 0; gr < 4; ++gr)
#pragma unroll
      for (int ct = 0; ct < 4; ++ct) cf[gr][ct] = bias4(fb2[16 * ct + m]);

#pragma unroll
    for (int hr = 0; hr < 2; ++hr) {
      f32x4 chh[4][4];
#pragma unroll
      for (int gr = 0; gr < 4; ++gr)
#pragma unroll
        for (int ct = 0; ct < 4; ++ct)
          chh[gr][ct] = bias4(fb1[16 * (4 * hr + ct) + m]);
#pragma unroll
      for (int ct = 0; ct < 4; ++ct)
#pragma unroll
        for (int kt = 0; kt < 2; ++kt) {
          s16x8 bh, bl; ldB(WH, WL, 79872, kt, 4 * hr + ct, 8, l, bh, bl);
#pragma unroll
          for (int gr = 0; gr < 4; ++gr)
            chh[gr][ct] = mf3(anh[gr][kt], anl[gr][kt], bh, bl, chh[gr][ct]);
        }
#pragma unroll
      for (int gr = 0; gr < 4; ++gr)
#pragma unroll
        for (int ct = 0; ct < 4; ++ct)
#pragma unroll
          for (int r = 0; r < 4; ++r) chh[gr][ct][r] = fmaxf(chh[gr][ct][r], 0.f);

      s16x8 hfh[4][2], hfl[4][2];
      trans_frags(sl, m, g, chh, hfh, hfl);
      stage_mm(WH, WL, 88064, 2 * hr, hfh, hfl, l, cf);
    }

    // AF store + props partials in the same A-layout pass
    float pp[4][4];
#pragma unroll
    for (int gr = 0; gr < 4; ++gr)
#pragma unroll
      for (int p = 0; p < 4; ++p) pp[gr][p] = 0.f;
#pragma unroll
    for (int h = 0; h < 2; ++h) {
      put_half(sl, m, g, cf, h);
      f32x4 pw0[4], pw1[4];
#pragma unroll
      for (int p = 0; p < 4; ++p) {
        const float* q = PW + p * 64 + 32 * h + 8 * g;
        pw0[p] = *(const f32x4*)q;
        pw1[p] = *(const f32x4*)(q + 4);
      }
#pragma unroll
      for (int gr = 0; gr < 4; ++gr) {
        float v[8];
        get_half(sl, m, g, gr, v);
        if (ok[gr]) {
          float* p = AF + (size_t)nat[gr] * 64 + 32 * h + 8 * g;
          *(float4*)p = make_float4(v[0], v[1], v[2], v[3]);
          *(float4*)(p + 4) = make_float4(v[4], v[5], v[6], v[7]);
        }
#pragma unroll
        for (int p = 0; p < 4; ++p)
#pragma unroll
          for (int i = 0; i < 4; ++i)
            pp[gr][p] += v[i] * pw0[p][i] + v[i + 4] * pw1[p][i];
      }
    }
    // reduce over g lanes (l^16, l^32), then lane (m,g) writes prop p=g
#pragma unroll
    for (int gr = 0; gr < 4; ++gr) {
      float r0 = pp[gr][0], r1 = pp[gr][1], r2 = pp[gr][2], r3 = pp[gr][3];
      r0 += __shfl_xor(r0, 16); r0 += __shfl_xor(r0, 32);
      r1 += __shfl_xor(r1, 16); r1 += __shfl_xor(r1, 32);
      r2 += __shfl_xor(r2, 16); r2 += __shfl_xor(r2, 32);
      r3 += __shfl_xor(r3, 16); r3 += __shfl_xor(r3, 32);
      float sel = (g == 0) ? r0 : (g == 1) ? r1 : (g == 2) ? r2 : r3;
      if (ok[gr]) PR[(size_t)nat[gr] * 4 + g] = sel + PB[g];
    }
  }
}

extern "C" void kernel_launch(void* const* d_in, const int* in_sizes, int n_in,
                              void* d_out, int out_size, void* d_ws, size_t ws_size,
                              hipStream_t stream) {
  const float* atom_fea = (const float*)d_in[0];
  const int*   nbr_idx  = (const int*)d_in[2];
  const float* ae_w   = (const float*)d_in[3];
  const float* ae_b   = (const float*)d_in[4];
  const float* msg_w1 = (const float*)d_in[7];
  const float* msg_b1 = (const float*)d_in[8];
  const float* msg_w2 = (const float*)d_in[9];
  const float* msg_b2 = (const float*)d_in[10];
  const float* upd_w1 = (const float*)d_in[11];
  const float* upd_b1 = (const float*)d_in[12];
  const float* upd_w2 = (const float*)d_in[13];
  const float* upd_b2 = (const float*)d_in[14];
  const float* fx_w1  = (const float*)d_in[15];
  const float* fx_b1  = (const float*)d_in[16];
  const float* fx_w2  = (const float*)d_in[17];
  const float* fx_b2  = (const float*)d_in[18];
  const float* prop_w = (const float*)d_in[19];
  const float* prop_b = (const float*)d_in[20];

  float* props   = (float*)d_out;
  float* af_reg  = props + (size_t)NA * 4;
  float* raw_reg = af_reg + (size_t)NA * 64;
  unsigned short* T0 = (unsigned short*)d_ws;
  unsigned short* T1 = T0 + (size_t)NA * 64;
  unsigned short* WHp = T1 + (size_t)NA * 64;
  unsigned short* WLp = WHp + 96256;

  k_prep<<<376, 256, 0, stream>>>(ae_w, msg_w1, msg_w2, upd_w1, upd_w2,
                                  fx_w1, fx_w2, WHp, WLp);

  int ngrid = (NA + 255) / 256;   // 1172
  k_embed_t<<<ngrid, 256, 0, stream>>>(atom_fea, WHp, WLp, ae_b, af_reg, T0);

  const int base0 = 6144, base1 = 6144 + 24576, base2 = 6144 + 2 * 24576;

  // layer 0: A0(af_reg) -> A1(raw_reg); T0 -> T1
  k_dense<1, 0><<<ngrid, 256, 0, stream>>>(
      af_reg, T0, nbr_idx, WHp, WLp,
      base0, base0 + 8192, base0 + 12288, base0 + 20480, base1,
      msg_b1, msg_b2, upd_b1, upd_b2,
      fx_b1, fx_b2, prop_w, prop_b,
      raw_reg, T1, nullptr, nullptr);

  // layer 1: A1(raw_reg) -> A2(af_reg); T1 -> T0
  k_dense<1, 0><<<ngrid, 256, 0, stream>>>(
      raw_reg, T1, nbr_idx, WHp, WLp,
      base1, base1 + 8192, base1 + 12288, base1 + 20480, base2,
      msg_b1 + 64, msg_b2 + 64, upd_b1 + 64, upd_b2 + 64,
      fx_b1, fx_b2, prop_w, prop_b,
      af_reg, T0, nullptr, nullptr);

  // layer 2 + fx: A2(af_reg) -> raw(raw_reg); af->af_reg, props->d_out
  k_dense<0, 1><<<ngrid, 256, 0, stream>>>(
      af_reg, T0, nbr_idx, WHp, WLp,
      base2, base2 + 8192, base2 + 12288, base2 + 20480, 0,
      msg_b1 + 128, msg_b2 + 128, upd_b1 + 128, upd_b2 + 128,
      fx_b1, fx_b2, prop_w, prop_b,
      raw_reg, T1, af_reg, props);
}

// Round 10
// 630.196 us; speedup vs baseline: 1.8800x; 1.8800x over previous
//
#include <hip/hip_runtime.h>
#include <hip/hip_bf16.h>

// AtomicScaleModule — CGCNN GNN forward, MFMA split-bf16 (~f32 accuracy).
// Structure = R7 verbatim (verified 667us: gather-first, no held fragments,
// no fences, two-phase [32][69] slab, one-pass transposes, (256,2)).
// Single delta vs R7: S stored in bf16 (like T) -> -230MB total HBM traffic.
// R8/R9 lesson (counters): holding A-fragments across the chain spills
// (WRITE_SIZE 356MB vs 115MB algorithmic) and s-before-gather serializes
// the 96 independent gather loads behind a GEMM. Do not re-introduce.
//   a = X@AE + ae_b
//   per layer: s = a@MW1[0:64]+b1 ; t = a@MW1[64:128]   (fused into producer)
//              H = sum_c relu(s + t[idx])               (gather @ head of dense)
//              agg = H@MW2 + 12*b2
//              u1 = relu(a@UW1[0:64] + agg@UW1[64:128] + ub1)
//              a' = relu(a + u1@UW2 + ub2)  (+ fused s,t of next layer)
//   af = relu(a@FX1+fb1)@FX2+fb2 ; props = af@PW^T+pb   (fused into last dense)
// S/T double-buffered (both bf16). nbr_fea / ne_w / ne_b dead.

constexpr int NA = 300000;

typedef short  s16x8 __attribute__((ext_vector_type(8)));
typedef float  f32x4 __attribute__((ext_vector_type(4)));

#define DEVFN static __device__ __forceinline__

DEVFN unsigned short f2bf(float x) {
  unsigned u = __float_as_uint(x);
  u += 0x7fffu + ((u >> 16) & 1u);          // RTNE
  return (unsigned short)(u >> 16);
}
DEVFN float bf2f(unsigned short h) { return __uint_as_float(((unsigned)h) << 16); }

// split x -> hi + lo bf16 pair (v_cvt_pk_bf16_f32-friendly)
DEVFN void mk_frag(const float* v, s16x8& hi, s16x8& lo) {
#pragma unroll
  for (int i = 0; i < 8; i += 2) {
    __hip_bfloat162 h2 = __float22bfloat162_rn(make_float2(v[i], v[i + 1]));
    float2 hf = __bfloat1622float2(h2);
    __hip_bfloat162 l2 = __float22bfloat162_rn(make_float2(v[i] - hf.x, v[i + 1] - hf.y));
    hi[i]     = (short)__bfloat16_as_ushort(h2.x);
    hi[i + 1] = (short)__bfloat16_as_ushort(h2.y);
    lo[i]     = (short)__bfloat16_as_ushort(l2.x);
    lo[i + 1] = (short)__bfloat16_as_ushort(l2.y);
  }
}

DEVFN f32x4 mf3(s16x8 ah, s16x8 al, s16x8 bh, s16x8 bl, f32x4 c) {
  c = __builtin_amdgcn_mfma_f32_16x16x32_bf16(al, bh, c, 0, 0, 0);
  c = __builtin_amdgcn_mfma_f32_16x16x32_bf16(ah, bl, c, 0, 0, 0);
  c = __builtin_amdgcn_mfma_f32_16x16x32_bf16(ah, bh, c, 0, 0, 0);
  return c;
}

DEVFN void ldB(const unsigned short* __restrict__ WH, const unsigned short* __restrict__ WL,
               int seg, int kt, int ct, int CT, int l, s16x8& bh, s16x8& bl) {
  size_t o = (size_t)seg + ((size_t)((kt * CT + ct) * 64 + l)) * 8;
  bh = *(const s16x8*)(WH + o);
  bl = *(const s16x8*)(WL + o);
}

DEVFN f32x4 bias4(float bv) { f32x4 c; c[0] = bv; c[1] = bv; c[2] = bv; c[3] = bv; return c; }

// one 64x64 GEMM stage for all 4 groups: 8 B-pairs, 96 MFMA.
DEVFN void stage_mm(const unsigned short* __restrict__ WH,
                    const unsigned short* __restrict__ WL,
                    int seg, int kt0,
                    const s16x8 (&fh)[4][2], const s16x8 (&fl)[4][2],
                    int l, f32x4 (&cc)[4][4]) {
#pragma unroll
  for (int ct = 0; ct < 4; ++ct)
#pragma unroll
    for (int kt = 0; kt < 2; ++kt) {
      s16x8 bh, bl; ldB(WH, WL, seg, kt0 + kt, ct, 4, l, bh, bl);
#pragma unroll
      for (int gr = 0; gr < 4; ++gr)
        cc[gr][ct] = mf3(fh[gr][kt], fl[gr][kt], bh, bl, cc[gr][ct]);
    }
}

// ---- two-phase slab transpose: half h covers features 32h..32h+31 ---------
DEVFN void put_half(float (*sl)[69], int m, int g, const f32x4 (&cc)[4][4], int h) {
#pragma unroll
  for (int gr = 0; gr < 4; ++gr)
#pragma unroll
    for (int c = 0; c < 2; ++c)
#pragma unroll
      for (int r = 0; r < 4; ++r)
        sl[16 * c + m][gr * 17 + 4 * g + r] = cc[gr][2 * h + c][r];
}
DEVFN void get_half(const float (*sl)[69], int m, int g, int gr, float* v) {
#pragma unroll
  for (int i = 0; i < 8; ++i) v[i] = sl[8 * g + i][gr * 17 + m];
}

DEVFN void trans_frags(float (*sl)[69], int m, int g, const f32x4 (&cc)[4][4],
                       s16x8 (&fh)[4][2], s16x8 (&fl)[4][2]) {
#pragma unroll
  for (int h = 0; h < 2; ++h) {
    put_half(sl, m, g, cc, h);
#pragma unroll
    for (int gr = 0; gr < 4; ++gr) {
      float v[8];
      get_half(sl, m, g, gr, v);
      mk_frag(v, fh[gr][h], fl[gr][h]);
    }
  }
}

// store 64 bf16 per atom (used for S and T)
DEVFN void trans_store_bf(float (*sl)[69], int m, int g, const f32x4 (&cc)[4][4],
                          unsigned short* __restrict__ B, const int (&nat)[4], const bool (&ok)[4]) {
#pragma unroll
  for (int h = 0; h < 2; ++h) {
    put_half(sl, m, g, cc, h);
#pragma unroll
    for (int gr = 0; gr < 4; ++gr) {
      float v[8];
      get_half(sl, m, g, gr, v);
      if (ok[gr]) {
        uint4 q;
        unsigned* qp = (unsigned*)&q;
#pragma unroll
        for (int p = 0; p < 4; ++p)
          qp[p] = (unsigned)f2bf(v[2 * p]) | ((unsigned)f2bf(v[2 * p + 1]) << 16);
        *(uint4*)(B + (size_t)nat[gr] * 64 + 32 * h + 8 * g) = q;
      }
    }
  }
}

// ---- weight pre-conversion to B-frag layout (hi/lo bf16) ------------------
// Segments (entry offsets): AE 0 (96x64); per layer base=6144+l*24576:
//   MW1 +0 (128x64), MW2 +8192 (64x64), UW1 +12288 (128x64), UW2 +20480 (64x64)
// FX1 79872 (64x128), FX2 88064 (128x64). Total 96256 entries.
__global__ __launch_bounds__(256) void k_prep(
    const float* __restrict__ ae, const float* __restrict__ mw1,
    const float* __restrict__ mw2, const float* __restrict__ uw1,
    const float* __restrict__ uw2, const float* __restrict__ fx1,
    const float* __restrict__ fx2,
    unsigned short* __restrict__ WH, unsigned short* __restrict__ WL) {
  int e = blockIdx.x * 256 + threadIdx.x;
  const float* src;
  int K, N, loc;
  if (e < 6144) { src = ae; K = 92; N = 64; loc = e; }
  else if (e < 79872) {
    int r = e - 6144;
    int lyr = r / 24576, q = r % 24576;
    size_t l64 = (size_t)lyr * 64;
    if (q < 8192)       { src = mw1 + l64 * 128; K = 128; N = 64; loc = q; }
    else if (q < 12288) { src = mw2 + l64 * 64;  K = 64;  N = 64; loc = q - 8192; }
    else if (q < 20480) { src = uw1 + l64 * 128; K = 128; N = 64; loc = q - 12288; }
    else                { src = uw2 + l64 * 64;  K = 64;  N = 64; loc = q - 20480; }
  }
  else if (e < 88064) { src = fx1; K = 64;  N = 128; loc = e - 79872; }
  else if (e < 96256) { src = fx2; K = 128; N = 64;  loc = e - 88064; }
  else return;
  int k = (N == 64) ? (loc >> 6) : (loc >> 7);
  int j = loc & (N - 1);
  float v = (k < K) ? src[(size_t)k * N + j] : 0.f;
  unsigned short h = f2bf(v);
  int CT = N >> 4;
  int lane = ((k >> 3) & 3) * 16 + (j & 15);
  int fidx = (e - loc) + (((k >> 5) * CT + (j >> 4)) * 64 + lane) * 8 + (k & 7);
  WH[fidx] = h;
  WL[fidx] = f2bf(v - bf2f(h));
}

// ---- embed + s,t of layer 0 (64 atoms per wave) ---------------------------
__global__ __launch_bounds__(256, 2) void k_embed_st(
    const float* __restrict__ X,
    const unsigned short* __restrict__ WH, const unsigned short* __restrict__ WL,
    const float* __restrict__ aeb, const float* __restrict__ b1,
    float* __restrict__ A0, unsigned short* __restrict__ S, unsigned short* __restrict__ T) {
  __shared__ float slab[4][32][69];
  int w = threadIdx.x >> 6, l = threadIdx.x & 63, m = l & 15, g = l >> 4;
  float (*sl)[69] = slab[w];
  int nbase = blockIdx.x * 256 + w * 64;
  int nat[4]; bool ok[4];
#pragma unroll
  for (int gr = 0; gr < 4; ++gr) {
    nat[gr] = nbase + gr * 16 + m;
    ok[gr] = nat[gr] < NA;
    if (!ok[gr]) nat[gr] = NA - 1;
  }

  // a0 = X@AE + ae_b ; X fragments built per kt to bound liveness
  f32x4 ca[4][4];
#pragma unroll
  for (int gr = 0; gr < 4; ++gr)
#pragma unroll
    for (int ct = 0; ct < 4; ++ct) ca[gr][ct] = bias4(aeb[16 * ct + m]);
#pragma unroll
  for (int kt = 0; kt < 3; ++kt) {
    s16x8 xh[4], xl[4];
#pragma unroll
    for (int gr = 0; gr < 4; ++gr) {
      const float* xr = X + (size_t)nat[gr] * 92;
      float v[8];
      if (kt < 2) {
        f32x4 a = *(const f32x4*)(xr + kt * 32 + g * 8);
        f32x4 b = *(const f32x4*)(xr + kt * 32 + g * 8 + 4);
        v[0]=a[0]; v[1]=a[1]; v[2]=a[2]; v[3]=a[3]; v[4]=b[0]; v[5]=b[1]; v[6]=b[2]; v[7]=b[3];
      } else if (g < 3) {
        f32x4 a = *(const f32x4*)(xr + 64 + g * 8);
        f32x4 b = *(const f32x4*)(xr + 64 + g * 8 + 4);
        v[0]=a[0]; v[1]=a[1]; v[2]=a[2]; v[3]=a[3]; v[4]=b[0]; v[5]=b[1]; v[6]=b[2]; v[7]=b[3];
      } else {
        f32x4 a = *(const f32x4*)(xr + 88);   // 88..91 valid, 92..95 pad
        v[0]=a[0]; v[1]=a[1]; v[2]=a[2]; v[3]=a[3]; v[4]=0.f; v[5]=0.f; v[6]=0.f; v[7]=0.f;
      }
      mk_frag(v, xh[gr], xl[gr]);
    }
#pragma unroll
    for (int ct = 0; ct < 4; ++ct) {
      s16x8 bh, bl; ldB(WH, WL, 0, kt, ct, 4, l, bh, bl);
#pragma unroll
      for (int gr = 0; gr < 4; ++gr)
        ca[gr][ct] = mf3(xh[gr], xl[gr], bh, bl, ca[gr][ct]);
    }
  }

  // transpose a0: store A0 coalesced + build fragments, one read pass
  s16x8 ah[4][2], al[4][2];
#pragma unroll
  for (int h = 0; h < 2; ++h) {
    put_half(sl, m, g, ca, h);
#pragma unroll
    for (int gr = 0; gr < 4; ++gr) {
      float v[8];
      get_half(sl, m, g, gr, v);
      if (ok[gr]) {
        float* p = A0 + (size_t)nat[gr] * 64 + 32 * h + 8 * g;
        *(float4*)p = make_float4(v[0], v[1], v[2], v[3]);
        *(float4*)(p + 4) = make_float4(v[4], v[5], v[6], v[7]);
      }
      mk_frag(v, ah[gr][h], al[gr][h]);
    }
  }

  // s = a0@MW1[0:64] + b1  (stored bf16)
  f32x4 cs[4][4];
#pragma unroll
  for (int gr = 0; gr < 4; ++gr)
#pragma unroll
    for (int ct = 0; ct < 4; ++ct) cs[gr][ct] = bias4(b1[16 * ct + m]);
  stage_mm(WH, WL, 6144, 0, ah, al, l, cs);
  trans_store_bf(sl, m, g, cs, S, nat, ok);

  // t = a0@MW1[64:128]
  f32x4 cT[4][4];
#pragma unroll
  for (int gr = 0; gr < 4; ++gr)
#pragma unroll
    for (int ct = 0; ct < 4; ++ct) cT[gr][ct] = bias4(0.f);
  stage_mm(WH, WL, 6144, 2, ah, al, l, cT);
  trans_store_bf(sl, m, g, cT, T, nat, ok);
}

// ---- fused: gather + dense chain (+ next-layer s,t | + fx tail) -----------
template <int HAS_NEXT, int HAS_FX>
__global__ __launch_bounds__(256, 2) void k_dense(
    const float* __restrict__ A, const unsigned short* __restrict__ S,
    const unsigned short* __restrict__ T, const int* __restrict__ IDX,
    const unsigned short* __restrict__ WH, const unsigned short* __restrict__ WL,
    int segW2, int segU1, int segU2, int segWn,
    const float* __restrict__ b2, const float* __restrict__ ub1,
    const float* __restrict__ ub2, const float* __restrict__ bn,
    const float* __restrict__ fb1, const float* __restrict__ fb2,
    const float* __restrict__ PW, const float* __restrict__ PB,
    float* __restrict__ Anew, unsigned short* __restrict__ Sout,
    unsigned short* __restrict__ Tout,
    float* __restrict__ AF, float* __restrict__ PR) {
  __shared__ float slab[4][32][69];
  int w = threadIdx.x >> 6, l = threadIdx.x & 63, m = l & 15, g = l >> 4;
  float (*sl)[69] = slab[w];
  int nbase = blockIdx.x * 256 + w * 64;
  int nat[4]; bool ok[4];
#pragma unroll
  for (int gr = 0; gr < 4; ++gr) {
    nat[gr] = nbase + gr * 16 + m;
    ok[gr] = nat[gr] < NA;
    if (!ok[gr]) nat[gr] = NA - 1;
  }

  // gather FIRST (R7 structure): H = sum_c relu(s + t[idx]); loads issue at
  // kernel entry, nothing upstream of them.
  s16x8 hh[4][2], hl[4][2];
#pragma unroll
  for (int gr = 0; gr < 4; ++gr) {
    const int* ip = IDX + (size_t)nat[gr] * 12;
    int4 i0 = *(const int4*)ip;
    int4 i1 = *(const int4*)(ip + 4);
    int4 i2 = *(const int4*)(ip + 8);
    int idxs[12] = {i0.x, i0.y, i0.z, i0.w, i1.x, i1.y, i1.z, i1.w,
                    i2.x, i2.y, i2.z, i2.w};
#pragma unroll
    for (int kt = 0; kt < 2; ++kt) {
      int f0 = 32 * kt + 8 * g;
      uint4 sv4 = *(const uint4*)(S + (size_t)nat[gr] * 64 + f0);
      float sv[8] = {
        bf2f((unsigned short)(sv4.x & 0xffff)), bf2f((unsigned short)(sv4.x >> 16)),
        bf2f((unsigned short)(sv4.y & 0xffff)), bf2f((unsigned short)(sv4.y >> 16)),
        bf2f((unsigned short)(sv4.z & 0xffff)), bf2f((unsigned short)(sv4.z >> 16)),
        bf2f((unsigned short)(sv4.w & 0xffff)), bf2f((unsigned short)(sv4.w >> 16))};
      float ha[8] = {0, 0, 0, 0, 0, 0, 0, 0};
#pragma unroll
      for (int c = 0; c < 12; ++c) {
        uint4 tv = *(const uint4*)(T + (size_t)idxs[c] * 64 + f0);
        ha[0] += fmaxf(sv[0] + bf2f((unsigned short)(tv.x & 0xffff)), 0.f);
        ha[1] += fmaxf(sv[1] + bf2f((unsigned short)(tv.x >> 16)), 0.f);
        ha[2] += fmaxf(sv[2] + bf2f((unsigned short)(tv.y & 0xffff)), 0.f);
        ha[3] += fmaxf(sv[3] + bf2f((unsigned short)(tv.y >> 16)), 0.f);
        ha[4] += fmaxf(sv[4] + bf2f((unsigned short)(tv.z & 0xffff)), 0.f);
        ha[5] += fmaxf(sv[5] + bf2f((unsigned short)(tv.z >> 16)), 0.f);
        ha[6] += fmaxf(sv[6] + bf2f((unsigned short)(tv.w & 0xffff)), 0.f);
        ha[7] += fmaxf(sv[7] + bf2f((unsigned short)(tv.w >> 16)), 0.f);
      }
      mk_frag(ha, hh[gr][kt], hl[gr][kt]);
    }
  }

  // agg = H@W2 + 12*b2
  f32x4 cg[4][4];
#pragma unroll
  for (int gr = 0; gr < 4; ++gr)
#pragma unroll
    for (int ct = 0; ct < 4; ++ct) cg[gr][ct] = bias4(12.f * b2[16 * ct + m]);
  stage_mm(WH, WL, segW2, 0, hh, hl, l, cg);

  // u1: a-part first (a frags die before q frags are built)
  f32x4 cu[4][4];
#pragma unroll
  for (int gr = 0; gr < 4; ++gr)
#pragma unroll
    for (int ct = 0; ct < 4; ++ct) cu[gr][ct] = bias4(ub1[16 * ct + m]);
  {
    s16x8 arh[4][2], arl[4][2];
#pragma unroll
    for (int gr = 0; gr < 4; ++gr)
#pragma unroll
      for (int kt = 0; kt < 2; ++kt) {
        const float* p8 = A + (size_t)nat[gr] * 64 + kt * 32 + g * 8;
        f32x4 a = *(const f32x4*)p8;
        f32x4 b = *(const f32x4*)(p8 + 4);
        float v[8] = {a[0], a[1], a[2], a[3], b[0], b[1], b[2], b[3]};
        mk_frag(v, arh[gr][kt], arl[gr][kt]);
      }
    stage_mm(WH, WL, segU1, 0, arh, arl, l, cu);
  }
  {
    s16x8 qh[4][2], ql[4][2];
    trans_frags(sl, m, g, cg, qh, ql);
    stage_mm(WH, WL, segU1, 2, qh, ql, l, cu);
  }
#pragma unroll
  for (int gr = 0; gr < 4; ++gr)
#pragma unroll
    for (int ct = 0; ct < 4; ++ct)
#pragma unroll
      for (int r = 0; r < 4; ++r) cu[gr][ct][r] = fmaxf(cu[gr][ct][r], 0.f);

  // upd = u1@U2 + ub2
  f32x4 cd[4][4];
#pragma unroll
  for (int gr = 0; gr < 4; ++gr)
#pragma unroll
    for (int ct = 0; ct < 4; ++ct) cd[gr][ct] = bias4(ub2[16 * ct + m]);
  {
    s16x8 uh[4][2], ul[4][2];
    trans_frags(sl, m, g, cu, uh, ul);
    stage_mm(WH, WL, segU2, 0, uh, ul, l, cd);
  }

  // a' = relu(a + upd): transpose, coalesced residual re-read (L2-hot),
  // coalesced store, fragments for next stages — one A-layout pass.
  s16x8 anh[4][2], anl[4][2];
#pragma unroll
  for (int h = 0; h < 2; ++h) {
    put_half(sl, m, g, cd, h);
#pragma unroll
    for (int gr = 0; gr < 4; ++gr) {
      float v[8];
      get_half(sl, m, g, gr, v);
      const float* ap = A + (size_t)nat[gr] * 64 + 32 * h + 8 * g;
      f32x4 a0 = *(const f32x4*)ap;
      f32x4 a1 = *(const f32x4*)(ap + 4);
#pragma unroll
      for (int i = 0; i < 4; ++i) {
        v[i]     = fmaxf(v[i] + a0[i], 0.f);
        v[i + 4] = fmaxf(v[i + 4] + a1[i], 0.f);
      }
      if (ok[gr]) {
        float* p = Anew + (size_t)nat[gr] * 64 + 32 * h + 8 * g;
        *(float4*)p = make_float4(v[0], v[1], v[2], v[3]);
        *(float4*)(p + 4) = make_float4(v[4], v[5], v[6], v[7]);
      }
      if constexpr (HAS_NEXT || HAS_FX) mk_frag(v, anh[gr][h], anl[gr][h]);
    }
  }

  if constexpr (HAS_NEXT) {
    // s_next (bf16)
    f32x4 cs[4][4];
#pragma unroll
    for (int gr = 0; gr < 4; ++gr)
#pragma unroll
      for (int ct = 0; ct < 4; ++ct) cs[gr][ct] = bias4(bn[16 * ct + m]);
    stage_mm(WH, WL, segWn, 0, anh, anl, l, cs);
    trans_store_bf(sl, m, g, cs, Sout, nat, ok);

    // t_next (bf16)
    f32x4 cT[4][4];
#pragma unroll
    for (int gr = 0; gr < 4; ++gr)
#pragma unroll
      for (int ct = 0; ct < 4; ++ct) cT[gr][ct] = bias4(0.f);
    stage_mm(WH, WL, segWn, 2, anh, anl, l, cT);
    trans_store_bf(sl, m, g, cT, Tout, nat, ok);
  }

  if constexpr (HAS_FX) {
    // af = relu(raw@FX1+fb1)@FX2+fb2, hidden 128 in two 64-col rounds
    f32x4 cf[4][4];
#pragma unroll
    for (int gr = 0; gr < 4; ++gr)
#pragma unroll
      for (int ct = 0; ct < 4; ++ct) cf[gr][ct] = bias4(fb2[16 * ct + m]);

#pragma unroll
    for (int hr = 0; hr < 2; ++hr) {
      f32x4 chh[4][4];
#pragma unroll
      for (int gr = 0; gr < 4; ++gr)
#pragma unroll
        for (int ct = 0; ct < 4; ++ct)
          chh[gr][ct] = bias4(fb1[16 * (4 * hr + ct) + m]);
#pragma unroll
      for (int ct = 0; ct < 4; ++ct)
#pragma unroll
        for (int kt = 0; kt < 2; ++kt) {
          s16x8 bh, bl; ldB(WH, WL, 79872, kt, 4 * hr + ct, 8, l, bh, bl);
#pragma unroll
          for (int gr = 0; gr < 4; ++gr)
            chh[gr][ct] = mf3(anh[gr][kt], anl[gr][kt], bh, bl, chh[gr][ct]);
        }
#pragma unroll
      for (int gr = 0; gr < 4; ++gr)
#pragma unroll
        for (int ct = 0; ct < 4; ++ct)
#pragma unroll
          for (int r = 0; r < 4; ++r) chh[gr][ct][r] = fmaxf(chh[gr][ct][r], 0.f);

      s16x8 hfh[4][2], hfl[4][2];
      trans_frags(sl, m, g, chh, hfh, hfl);
      stage_mm(WH, WL, 88064, 2 * hr, hfh, hfl, l, cf);
    }

    // AF store + props partials in the same A-layout pass
    float pp[4][4];
#pragma unroll
    for (int gr = 0; gr < 4; ++gr)
#pragma unroll
      for (int p = 0; p < 4; ++p) pp[gr][p] = 0.f;
#pragma unroll
    for (int h = 0; h < 2; ++h) {
      put_half(sl, m, g, cf, h);
      f32x4 pw0[4], pw1[4];
#pragma unroll
      for (int p = 0; p < 4; ++p) {
        const float* q = PW + p * 64 + 32 * h + 8 * g;
        pw0[p] = *(const f32x4*)q;
        pw1[p] = *(const f32x4*)(q + 4);
      }
#pragma unroll
      for (int gr = 0; gr < 4; ++gr) {
        float v[8];
        get_half(sl, m, g, gr, v);
        if (ok[gr]) {
          float* p = AF + (size_t)nat[gr] * 64 + 32 * h + 8 * g;
          *(float4*)p = make_float4(v[0], v[1], v[2], v[3]);
          *(float4*)(p + 4) = make_float4(v[4], v[5], v[6], v[7]);
        }
#pragma unroll
        for (int p = 0; p < 4; ++p)
#pragma unroll
          for (int i = 0; i < 4; ++i)
            pp[gr][p] += v[i] * pw0[p][i] + v[i + 4] * pw1[p][i];
      }
    }
    // reduce over g lanes (l^16, l^32), then lane (m,g) writes prop p=g
#pragma unroll
    for (int gr = 0; gr < 4; ++gr) {
      float r0 = pp[gr][0], r1 = pp[gr][1], r2 = pp[gr][2], r3 = pp[gr][3];
      r0 += __shfl_xor(r0, 16); r0 += __shfl_xor(r0, 32);
      r1 += __shfl_xor(r1, 16); r1 += __shfl_xor(r1, 32);
      r2 += __shfl_xor(r2, 16); r2 += __shfl_xor(r2, 32);
      r3 += __shfl_xor(r3, 16); r3 += __shfl_xor(r3, 32);
      float sel = (g == 0) ? r0 : (g == 1) ? r1 : (g == 2) ? r2 : r3;
      if (ok[gr]) PR[(size_t)nat[gr] * 4 + g] = sel + PB[g];
    }
  }
}

extern "C" void kernel_launch(void* const* d_in, const int* in_sizes, int n_in,
                              void* d_out, int out_size, void* d_ws, size_t ws_size,
                              hipStream_t stream) {
  const float* atom_fea = (const float*)d_in[0];
  const int*   nbr_idx  = (const int*)d_in[2];
  const float* ae_w   = (const float*)d_in[3];
  const float* ae_b   = (const float*)d_in[4];
  const float* msg_w1 = (const float*)d_in[7];
  const float* msg_b1 = (const float*)d_in[8];
  const float* msg_w2 = (const float*)d_in[9];
  const float* msg_b2 = (const float*)d_in[10];
  const float* upd_w1 = (const float*)d_in[11];
  const float* upd_b1 = (const float*)d_in[12];
  const float* upd_w2 = (const float*)d_in[13];
  const float* upd_b2 = (const float*)d_in[14];
  const float* fx_w1  = (const float*)d_in[15];
  const float* fx_b1  = (const float*)d_in[16];
  const float* fx_w2  = (const float*)d_in[17];
  const float* fx_b2  = (const float*)d_in[18];
  const float* prop_w = (const float*)d_in[19];
  const float* prop_b = (const float*)d_in[20];

  float* props   = (float*)d_out;
  float* af_reg  = props + (size_t)NA * 4;
  float* raw_reg = af_reg + (size_t)NA * 64;
  unsigned short* S0 = (unsigned short*)d_ws;
  unsigned short* S1 = S0 + (size_t)NA * 64;
  unsigned short* T0 = S1 + (size_t)NA * 64;
  unsigned short* T1 = T0 + (size_t)NA * 64;
  unsigned short* WHp = T1 + (size_t)NA * 64;
  unsigned short* WLp = WHp + 96256;

  k_prep<<<376, 256, 0, stream>>>(ae_w, msg_w1, msg_w2, upd_w1, upd_w2,
                                  fx_w1, fx_w2, WHp, WLp);

  int ngrid = (NA + 255) / 256;   // 1172
  k_embed_st<<<ngrid, 256, 0, stream>>>(atom_fea, WHp, WLp, ae_b, msg_b1,
                                        af_reg, S0, T0);

  const int base0 = 6144, base1 = 6144 + 24576, base2 = 6144 + 2 * 24576;

  // layer 0: A0(af_reg) -> A1(raw_reg); S0/T0 -> S1/T1
  k_dense<1, 0><<<ngrid, 256, 0, stream>>>(
      af_reg, S0, T0, nbr_idx, WHp, WLp,
      base0 + 8192, base0 + 12288, base0 + 20480, base1,
      msg_b2, upd_b1, upd_b2, msg_b1 + 64,
      fx_b1, fx_b2, prop_w, prop_b,
      raw_reg, S1, T1, nullptr, nullptr);

  // layer 1: A1(raw_reg) -> A2(af_reg); S1/T1 -> S0/T0
  k_dense<1, 0><<<ngrid, 256, 0, stream>>>(
      raw_reg, S1, T1, nbr_idx, WHp, WLp,
      base1 + 8192, base1 + 12288, base1 + 20480, base2,
      msg_b2 + 64, upd_b1 + 64, upd_b2 + 64, msg_b1 + 128,
      fx_b1, fx_b2, prop_w, prop_b,
      af_reg, S0, T0, nullptr, nullptr);

  // layer 2 + fx: A2(af_reg) -> raw(raw_reg); af->af_reg, props->d_out
  k_dense<0, 1><<<ngrid, 256, 0, stream>>>(
      af_reg, S0, T0, nbr_idx, WHp, WLp,
      base2 + 8192, base2 + 12288, base2 + 20480, 0,
      msg_b2 + 128, upd_b1 + 128, upd_b2 + 128, msg_b1,
      fx_b1, fx_b2, prop_w, prop_b,
      raw_reg, S1, T1, af_reg, props);
}

// Round 11
// 545.997 us; speedup vs baseline: 2.1699x; 1.1542x over previous
//
#include <hip/hip_runtime.h>
#include <hip/hip_bf16.h>

// AtomicScaleModule — CGCNN GNN forward, MFMA split-bf16 (~f32 accuracy).
// R10 structure (gather-first, no fences, two-phase [32][69] slab, (256,2)).
// Deltas vs R10:
//  * A plane stored bf16 and SINGLE-buffered in-place (A rows are only ever
//    touched by their owning atom's thread-quad -> read-then-write is safe).
//  * S single-buffered (own-row read at head, own-row write at tail).
//  * bf16 A => a-fragments have lo==0: u1 a-part uses 2-term MFMA and a
//    straight s16x8 load (no split VALU).
//  * Only T is double-buffered (cross-block neighbor reads).
//   a = X@AE + ae_b
//   per layer: s = a@MW1[0:64]+b1 ; t = a@MW1[64:128]   (fused into producer)
//              H = sum_c relu(s + t[idx])               (gather @ head of dense)
//              agg = H@MW2 + 12*b2
//              u1 = relu(a@UW1[0:64] + agg@UW1[64:128] + ub1)
//              a' = relu(a + u1@UW2 + ub2)  (+ fused s,t of next layer)
//   af = relu(a@FX1+fb1)@FX2+fb2 ; props = af@PW^T+pb   (fused into last dense)
// nbr_fea / ne_w / ne_b dead.

constexpr int NA = 300000;

typedef short  s16x8 __attribute__((ext_vector_type(8)));
typedef float  f32x4 __attribute__((ext_vector_type(4)));

#define DEVFN static __device__ __forceinline__

DEVFN unsigned short f2bf(float x) {
  unsigned u = __float_as_uint(x);
  u += 0x7fffu + ((u >> 16) & 1u);          // RTNE
  return (unsigned short)(u >> 16);
}
DEVFN float bf2f(unsigned short h) { return __uint_as_float(((unsigned)h) << 16); }

// split x -> hi + lo bf16 pair (v_cvt_pk_bf16_f32-friendly)
DEVFN void mk_frag(const float* v, s16x8& hi, s16x8& lo) {
#pragma unroll
  for (int i = 0; i < 8; i += 2) {
    __hip_bfloat162 h2 = __float22bfloat162_rn(make_float2(v[i], v[i + 1]));
    float2 hf = __bfloat1622float2(h2);
    __hip_bfloat162 l2 = __float22bfloat162_rn(make_float2(v[i] - hf.x, v[i + 1] - hf.y));
    hi[i]     = (short)__bfloat16_as_ushort(h2.x);
    hi[i + 1] = (short)__bfloat16_as_ushort(h2.y);
    lo[i]     = (short)__bfloat16_as_ushort(l2.x);
    lo[i + 1] = (short)__bfloat16_as_ushort(l2.y);
  }
}

DEVFN f32x4 mf3(s16x8 ah, s16x8 al, s16x8 bh, s16x8 bl, f32x4 c) {
  c = __builtin_amdgcn_mfma_f32_16x16x32_bf16(al, bh, c, 0, 0, 0);
  c = __builtin_amdgcn_mfma_f32_16x16x32_bf16(ah, bl, c, 0, 0, 0);
  c = __builtin_amdgcn_mfma_f32_16x16x32_bf16(ah, bh, c, 0, 0, 0);
  return c;
}

DEVFN f32x4 mf2(s16x8 ah, s16x8 bh, s16x8 bl, f32x4 c) {   // a exact in bf16
  c = __builtin_amdgcn_mfma_f32_16x16x32_bf16(ah, bl, c, 0, 0, 0);
  c = __builtin_amdgcn_mfma_f32_16x16x32_bf16(ah, bh, c, 0, 0, 0);
  return c;
}

DEVFN void ldB(const unsigned short* __restrict__ WH, const unsigned short* __restrict__ WL,
               int seg, int kt, int ct, int CT, int l, s16x8& bh, s16x8& bl) {
  size_t o = (size_t)seg + ((size_t)((kt * CT + ct) * 64 + l)) * 8;
  bh = *(const s16x8*)(WH + o);
  bl = *(const s16x8*)(WL + o);
}

DEVFN f32x4 bias4(float bv) { f32x4 c; c[0] = bv; c[1] = bv; c[2] = bv; c[3] = bv; return c; }

// one 64x64 GEMM stage for all 4 groups: 8 B-pairs, 96 MFMA (3-term).
DEVFN void stage_mm(const unsigned short* __restrict__ WH,
                    const unsigned short* __restrict__ WL,
                    int seg, int kt0,
                    const s16x8 (&fh)[4][2], const s16x8 (&fl)[4][2],
                    int l, f32x4 (&cc)[4][4]) {
#pragma unroll
  for (int ct = 0; ct < 4; ++ct)
#pragma unroll
    for (int kt = 0; kt < 2; ++kt) {
      s16x8 bh, bl; ldB(WH, WL, seg, kt0 + kt, ct, 4, l, bh, bl);
#pragma unroll
      for (int gr = 0; gr < 4; ++gr)
        cc[gr][ct] = mf3(fh[gr][kt], fl[gr][kt], bh, bl, cc[gr][ct]);
    }
}

// 2-term variant for exact-bf16 A operand (lo==0): 64 MFMA.
DEVFN void stage_mm2(const unsigned short* __restrict__ WH,
                     const unsigned short* __restrict__ WL,
                     int seg, int kt0,
                     const s16x8 (&fh)[4][2],
                     int l, f32x4 (&cc)[4][4]) {
#pragma unroll
  for (int ct = 0; ct < 4; ++ct)
#pragma unroll
    for (int kt = 0; kt < 2; ++kt) {
      s16x8 bh, bl; ldB(WH, WL, seg, kt0 + kt, ct, 4, l, bh, bl);
#pragma unroll
      for (int gr = 0; gr < 4; ++gr)
        cc[gr][ct] = mf2(fh[gr][kt], bh, bl, cc[gr][ct]);
    }
}

// ---- two-phase slab transpose: half h covers features 32h..32h+31 ---------
DEVFN void put_half(float (*sl)[69], int m, int g, const f32x4 (&cc)[4][4], int h) {
#pragma unroll
  for (int gr = 0; gr < 4; ++gr)
#pragma unroll
    for (int c = 0; c < 2; ++c)
#pragma unroll
      for (int r = 0; r < 4; ++r)
        sl[16 * c + m][gr * 17 + 4 * g + r] = cc[gr][2 * h + c][r];
}
DEVFN void get_half(const float (*sl)[69], int m, int g, int gr, float* v) {
#pragma unroll
  for (int i = 0; i < 8; ++i) v[i] = sl[8 * g + i][gr * 17 + m];
}

DEVFN void trans_frags(float (*sl)[69], int m, int g, const f32x4 (&cc)[4][4],
                       s16x8 (&fh)[4][2], s16x8 (&fl)[4][2]) {
#pragma unroll
  for (int h = 0; h < 2; ++h) {
    put_half(sl, m, g, cc, h);
#pragma unroll
    for (int gr = 0; gr < 4; ++gr) {
      float v[8];
      get_half(sl, m, g, gr, v);
      mk_frag(v, fh[gr][h], fl[gr][h]);
    }
  }
}

DEVFN void pack_store8(unsigned short* __restrict__ p, const float* v) {
  uint4 q;
  unsigned* qp = (unsigned*)&q;
#pragma unroll
  for (int i = 0; i < 4; ++i)
    qp[i] = (unsigned)f2bf(v[2 * i]) | ((unsigned)f2bf(v[2 * i + 1]) << 16);
  *(uint4*)p = q;
}

// store 64 bf16 per atom (used for S and T)
DEVFN void trans_store_bf(float (*sl)[69], int m, int g, const f32x4 (&cc)[4][4],
                          unsigned short* __restrict__ B, const int (&nat)[4], const bool (&ok)[4]) {
#pragma unroll
  for (int h = 0; h < 2; ++h) {
    put_half(sl, m, g, cc, h);
#pragma unroll
    for (int gr = 0; gr < 4; ++gr) {
      float v[8];
      get_half(sl, m, g, gr, v);
      if (ok[gr]) pack_store8(B + (size_t)nat[gr] * 64 + 32 * h + 8 * g, v);
    }
  }
}

// ---- weight pre-conversion to B-frag layout (hi/lo bf16) ------------------
// Segments (entry offsets): AE 0 (96x64); per layer base=6144+l*24576:
//   MW1 +0 (128x64), MW2 +8192 (64x64), UW1 +12288 (128x64), UW2 +20480 (64x64)
// FX1 79872 (64x128), FX2 88064 (128x64). Total 96256 entries.
__global__ __launch_bounds__(256) void k_prep(
    const float* __restrict__ ae, const float* __restrict__ mw1,
    const float* __restrict__ mw2, const float* __restrict__ uw1,
    const float* __restrict__ uw2, const float* __restrict__ fx1,
    const float* __restrict__ fx2,
    unsigned short* __restrict__ WH, unsigned short* __restrict__ WL) {
  int e = blockIdx.x * 256 + threadIdx.x;
  const float* src;
  int K, N, loc;
  if (e < 6144) { src = ae; K = 92; N = 64; loc = e; }
  else if (e < 79872) {
    int r = e - 6144;
    int lyr = r / 24576, q = r % 24576;
    size_t l64 = (size_t)lyr * 64;
    if (q < 8192)       { src = mw1 + l64 * 128; K = 128; N = 64; loc = q; }
    else if (q < 12288) { src = mw2 + l64 * 64;  K = 64;  N = 64; loc = q - 8192; }
    else if (q < 20480) { src = uw1 + l64 * 128; K = 128; N = 64; loc = q - 12288; }
    else                { src = uw2 + l64 * 64;  K = 64;  N = 64; loc = q - 20480; }
  }
  else if (e < 88064) { src = fx1; K = 64;  N = 128; loc = e - 79872; }
  else if (e < 96256) { src = fx2; K = 128; N = 64;  loc = e - 88064; }
  else return;
  int k = (N == 64) ? (loc >> 6) : (loc >> 7);
  int j = loc & (N - 1);
  float v = (k < K) ? src[(size_t)k * N + j] : 0.f;
  unsigned short h = f2bf(v);
  int CT = N >> 4;
  int lane = ((k >> 3) & 3) * 16 + (j & 15);
  int fidx = (e - loc) + (((k >> 5) * CT + (j >> 4)) * 64 + lane) * 8 + (k & 7);
  WH[fidx] = h;
  WL[fidx] = f2bf(v - bf2f(h));
}

// ---- embed + s,t of layer 0 (64 atoms per wave) ---------------------------
__global__ __launch_bounds__(256, 2) void k_embed_st(
    const float* __restrict__ X,
    const unsigned short* __restrict__ WH, const unsigned short* __restrict__ WL,
    const float* __restrict__ aeb, const float* __restrict__ b1,
    unsigned short* __restrict__ A, unsigned short* __restrict__ S,
    unsigned short* __restrict__ T) {
  __shared__ float slab[4][32][69];
  int w = threadIdx.x >> 6, l = threadIdx.x & 63, m = l & 15, g = l >> 4;
  float (*sl)[69] = slab[w];
  int nbase = blockIdx.x * 256 + w * 64;
  int nat[4]; bool ok[4];
#pragma unroll
  for (int gr = 0; gr < 4; ++gr) {
    nat[gr] = nbase + gr * 16 + m;
    ok[gr] = nat[gr] < NA;
    if (!ok[gr]) nat[gr] = NA - 1;
  }

  // a0 = X@AE + ae_b ; X fragments built per kt to bound liveness
  f32x4 ca[4][4];
#pragma unroll
  for (int gr = 0; gr < 4; ++gr)
#pragma unroll
    for (int ct = 0; ct < 4; ++ct) ca[gr][ct] = bias4(aeb[16 * ct + m]);
#pragma unroll
  for (int kt = 0; kt < 3; ++kt) {
    s16x8 xh[4], xl[4];
#pragma unroll
    for (int gr = 0; gr < 4; ++gr) {
      const float* xr = X + (size_t)nat[gr] * 92;
      float v[8];
      if (kt < 2) {
        f32x4 a = *(const f32x4*)(xr + kt * 32 + g * 8);
        f32x4 b = *(const f32x4*)(xr + kt * 32 + g * 8 + 4);
        v[0]=a[0]; v[1]=a[1]; v[2]=a[2]; v[3]=a[3]; v[4]=b[0]; v[5]=b[1]; v[6]=b[2]; v[7]=b[3];
      } else if (g < 3) {
        f32x4 a = *(const f32x4*)(xr + 64 + g * 8);
        f32x4 b = *(const f32x4*)(xr + 64 + g * 8 + 4);
        v[0]=a[0]; v[1]=a[1]; v[2]=a[2]; v[3]=a[3]; v[4]=b[0]; v[5]=b[1]; v[6]=b[2]; v[7]=b[3];
      } else {
        f32x4 a = *(const f32x4*)(xr + 88);   // 88..91 valid, 92..95 pad
        v[0]=a[0]; v[1]=a[1]; v[2]=a[2]; v[3]=a[3]; v[4]=0.f; v[5]=0.f; v[6]=0.f; v[7]=0.f;
      }
      mk_frag(v, xh[gr], xl[gr]);
    }
#pragma unroll
    for (int ct = 0; ct < 4; ++ct) {
      s16x8 bh, bl; ldB(WH, WL, 0, kt, ct, 4, l, bh, bl);
#pragma unroll
      for (int gr = 0; gr < 4; ++gr)
        ca[gr][ct] = mf3(xh[gr], xl[gr], bh, bl, ca[gr][ct]);
    }
  }

  // transpose a0: store A (bf16) + build fragments, one read pass
  s16x8 ah[4][2], al[4][2];
#pragma unroll
  for (int h = 0; h < 2; ++h) {
    put_half(sl, m, g, ca, h);
#pragma unroll
    for (int gr = 0; gr < 4; ++gr) {
      float v[8];
      get_half(sl, m, g, gr, v);
      if (ok[gr]) pack_store8(A + (size_t)nat[gr] * 64 + 32 * h + 8 * g, v);
      mk_frag(v, ah[gr][h], al[gr][h]);
    }
  }

  // s = a0@MW1[0:64] + b1  (stored bf16)
  f32x4 cs[4][4];
#pragma unroll
  for (int gr = 0; gr < 4; ++gr)
#pragma unroll
    for (int ct = 0; ct < 4; ++ct) cs[gr][ct] = bias4(b1[16 * ct + m]);
  stage_mm(WH, WL, 6144, 0, ah, al, l, cs);
  trans_store_bf(sl, m, g, cs, S, nat, ok);

  // t = a0@MW1[64:128]
  f32x4 cT[4][4];
#pragma unroll
  for (int gr = 0; gr < 4; ++gr)
#pragma unroll
    for (int ct = 0; ct < 4; ++ct) cT[gr][ct] = bias4(0.f);
  stage_mm(WH, WL, 6144, 2, ah, al, l, cT);
  trans_store_bf(sl, m, g, cT, T, nat, ok);
}

// ---- fused: gather + dense chain (+ next-layer s,t | + fx tail) -----------
// A and S are updated IN-PLACE (own-row read-then-write, race-free).
template <int HAS_NEXT, int HAS_FX>
__global__ __launch_bounds__(256, 2) void k_dense(
    unsigned short* __restrict__ A, unsigned short* __restrict__ S,
    const unsigned short* __restrict__ T, const int* __restrict__ IDX,
    const unsigned short* __restrict__ WH, const unsigned short* __restrict__ WL,
    int segW2, int segU1, int segU2, int segWn,
    const float* __restrict__ b2, const float* __restrict__ ub1,
    const float* __restrict__ ub2, const float* __restrict__ bn,
    const float* __restrict__ fb1, const float* __restrict__ fb2,
    const float* __restrict__ PW, const float* __restrict__ PB,
    unsigned short* __restrict__ Tout,
    float* __restrict__ RawOut, float* __restrict__ AF, float* __restrict__ PR) {
  __shared__ float slab[4][32][69];
  int w = threadIdx.x >> 6, l = threadIdx.x & 63, m = l & 15, g = l >> 4;
  float (*sl)[69] = slab[w];
  int nbase = blockIdx.x * 256 + w * 64;
  int nat[4]; bool ok[4];
#pragma unroll
  for (int gr = 0; gr < 4; ++gr) {
    nat[gr] = nbase + gr * 16 + m;
    ok[gr] = nat[gr] < NA;
    if (!ok[gr]) nat[gr] = NA - 1;
  }

  // gather FIRST: H = sum_c relu(s + t[idx]); loads issue at kernel entry.
  s16x8 hh[4][2], hl[4][2];
#pragma unroll
  for (int gr = 0; gr < 4; ++gr) {
    const int* ip = IDX + (size_t)nat[gr] * 12;
    int4 i0 = *(const int4*)ip;
    int4 i1 = *(const int4*)(ip + 4);
    int4 i2 = *(const int4*)(ip + 8);
    int idxs[12] = {i0.x, i0.y, i0.z, i0.w, i1.x, i1.y, i1.z, i1.w,
                    i2.x, i2.y, i2.z, i2.w};
#pragma unroll
    for (int kt = 0; kt < 2; ++kt) {
      int f0 = 32 * kt + 8 * g;
      uint4 sv4 = *(const uint4*)(S + (size_t)nat[gr] * 64 + f0);
      float sv[8] = {
        bf2f((unsigned short)(sv4.x & 0xffff)), bf2f((unsigned short)(sv4.x >> 16)),
        bf2f((unsigned short)(sv4.y & 0xffff)), bf2f((unsigned short)(sv4.y >> 16)),
        bf2f((unsigned short)(sv4.z & 0xffff)), bf2f((unsigned short)(sv4.z >> 16)),
        bf2f((unsigned short)(sv4.w & 0xffff)), bf2f((unsigned short)(sv4.w >> 16))};
      float ha[8] = {0, 0, 0, 0, 0, 0, 0, 0};
#pragma unroll
      for (int c = 0; c < 12; ++c) {
        uint4 tv = *(const uint4*)(T + (size_t)idxs[c] * 64 + f0);
        ha[0] += fmaxf(sv[0] + bf2f((unsigned short)(tv.x & 0xffff)), 0.f);
        ha[1] += fmaxf(sv[1] + bf2f((unsigned short)(tv.x >> 16)), 0.f);
        ha[2] += fmaxf(sv[2] + bf2f((unsigned short)(tv.y & 0xffff)), 0.f);
        ha[3] += fmaxf(sv[3] + bf2f((unsigned short)(tv.y >> 16)), 0.f);
        ha[4] += fmaxf(sv[4] + bf2f((unsigned short)(tv.z & 0xffff)), 0.f);
        ha[5] += fmaxf(sv[5] + bf2f((unsigned short)(tv.z >> 16)), 0.f);
        ha[6] += fmaxf(sv[6] + bf2f((unsigned short)(tv.w & 0xffff)), 0.f);
        ha[7] += fmaxf(sv[7] + bf2f((unsigned short)(tv.w >> 16)), 0.f);
      }
      mk_frag(ha, hh[gr][kt], hl[gr][kt]);
    }
  }

  // agg = H@W2 + 12*b2
  f32x4 cg[4][4];
#pragma unroll
  for (int gr = 0; gr < 4; ++gr)
#pragma unroll
    for (int ct = 0; ct < 4; ++ct) cg[gr][ct] = bias4(12.f * b2[16 * ct + m]);
  stage_mm(WH, WL, segW2, 0, hh, hl, l, cg);

  // u1: a-part (exact bf16 A -> 2-term, straight loads), then agg-part
  f32x4 cu[4][4];
#pragma unroll
  for (int gr = 0; gr < 4; ++gr)
#pragma unroll
    for (int ct = 0; ct < 4; ++ct) cu[gr][ct] = bias4(ub1[16 * ct + m]);
  {
    s16x8 arh[4][2];
#pragma unroll
    for (int gr = 0; gr < 4; ++gr)
#pragma unroll
      for (int kt = 0; kt < 2; ++kt)
        arh[gr][kt] = *(const s16x8*)(A + (size_t)nat[gr] * 64 + kt * 32 + g * 8);
    stage_mm2(WH, WL, segU1, 0, arh, l, cu);
  }
  {
    s16x8 qh[4][2], ql[4][2];
    trans_frags(sl, m, g, cg, qh, ql);
    stage_mm(WH, WL, segU1, 2, qh, ql, l, cu);
  }
#pragma unroll
  for (int gr = 0; gr < 4; ++gr)
#pragma unroll
    for (int ct = 0; ct < 4; ++ct)
#pragma unroll
      for (int r = 0; r < 4; ++r) cu[gr][ct][r] = fmaxf(cu[gr][ct][r], 0.f);

  // upd = u1@U2 + ub2
  f32x4 cd[4][4];
#pragma unroll
  for (int gr = 0; gr < 4; ++gr)
#pragma unroll
    for (int ct = 0; ct < 4; ++ct) cd[gr][ct] = bias4(ub2[16 * ct + m]);
  {
    s16x8 uh[4][2], ul[4][2];
    trans_frags(sl, m, g, cu, uh, ul);
    stage_mm(WH, WL, segU2, 0, uh, ul, l, cd);
  }

  // a' = relu(a + upd): transpose, residual re-read (bf16, L2-hot),
  // store (bf16 in-place | f32 raw), fragments for next stages.
  s16x8 anh[4][2], anl[4][2];
#pragma unroll
  for (int h = 0; h < 2; ++h) {
    put_half(sl, m, g, cd, h);
#pragma unroll
    for (int gr = 0; gr < 4; ++gr) {
      float v[8];
      get_half(sl, m, g, gr, v);
      uint4 au = *(const uint4*)(A + (size_t)nat[gr] * 64 + 32 * h + 8 * g);
      float av[8] = {
        bf2f((unsigned short)(au.x & 0xffff)), bf2f((unsigned short)(au.x >> 16)),
        bf2f((unsigned short)(au.y & 0xffff)), bf2f((unsigned short)(au.y >> 16)),
        bf2f((unsigned short)(au.z & 0xffff)), bf2f((unsigned short)(au.z >> 16)),
        bf2f((unsigned short)(au.w & 0xffff)), bf2f((unsigned short)(au.w >> 16))};
#pragma unroll
      for (int i = 0; i < 8; ++i) v[i] = fmaxf(v[i] + av[i], 0.f);
      if constexpr (HAS_FX) {
        if (ok[gr]) {
          float* p = RawOut + (size_t)nat[gr] * 64 + 32 * h + 8 * g;
          *(float4*)p = make_float4(v[0], v[1], v[2], v[3]);
          *(float4*)(p + 4) = make_float4(v[4], v[5], v[6], v[7]);
        }
      } else {
        if (ok[gr]) pack_store8(A + (size_t)nat[gr] * 64 + 32 * h + 8 * g, v);
      }
      if constexpr (HAS_NEXT || HAS_FX) mk_frag(v, anh[gr][h], anl[gr][h]);
    }
  }

  if constexpr (HAS_NEXT) {
    // s_next (bf16, in-place over S)
    f32x4 cs[4][4];
#pragma unroll
    for (int gr = 0; gr < 4; ++gr)
#pragma unroll
      for (int ct = 0; ct < 4; ++ct) cs[gr][ct] = bias4(bn[16 * ct + m]);
    stage_mm(WH, WL, segWn, 0, anh, anl, l, cs);
    trans_store_bf(sl, m, g, cs, S, nat, ok);

    // t_next (bf16, ping-pong buffer)
    f32x4 cT[4][4];
#pragma unroll
    for (int gr = 0; gr < 4; ++gr)
#pragma unroll
      for (int ct = 0; ct < 4; ++ct) cT[gr][ct] = bias4(0.f);
    stage_mm(WH, WL, segWn, 2, anh, anl, l, cT);
    trans_store_bf(sl, m, g, cT, Tout, nat, ok);
  }

  if constexpr (HAS_FX) {
    // af = relu(raw@FX1+fb1)@FX2+fb2, hidden 128 in two 64-col rounds
    f32x4 cf[4][4];
#pragma unroll
    for (int gr = 0; gr < 4; ++gr)
#pragma unroll
      for (int ct = 0; ct < 4; ++ct) cf[gr][ct] = bias4(fb2[16 * ct + m]);

#pragma unroll
    for (int hr = 0; hr < 2; ++hr) {
      f32x4 chh[4][4];
#pragma unroll
      for (int gr = 0; gr < 4; ++gr)
#pragma unroll
        for (int ct = 0; ct < 4; ++ct)
          chh[gr][ct] = bias4(fb1[16 * (4 * hr + ct) + m]);
#pragma unroll
      for (int ct = 0; ct < 4; ++ct)
#pragma unroll
        for (int kt = 0; kt < 2; ++kt) {
          s16x8 bh, bl; ldB(WH, WL, 79872, kt, 4 * hr + ct, 8, l, bh, bl);
#pragma unroll
          for (int gr = 0; gr < 4; ++gr)
            chh[gr][ct] = mf3(anh[gr][kt], anl[gr][kt], bh, bl, chh[gr][ct]);
        }
#pragma unroll
      for (int gr = 0; gr < 4; ++gr)
#pragma unroll
        for (int ct = 0; ct < 4; ++ct)
#pragma unroll
          for (int r = 0; r < 4; ++r) chh[gr][ct][r] = fmaxf(chh[gr][ct][r], 0.f);

      s16x8 hfh[4][2], hfl[4][2];
      trans_frags(sl, m, g, chh, hfh, hfl);
      stage_mm(WH, WL, 88064, 2 * hr, hfh, hfl, l, cf);
    }

    // AF store + props partials in the same A-layout pass
    float pp[4][4];
#pragma unroll
    for (int gr = 0; gr < 4; ++gr)
#pragma unroll
      for (int p = 0; p < 4; ++p) pp[gr][p] = 0.f;
#pragma unroll
    for (int h = 0; h < 2; ++h) {
      put_half(sl, m, g, cf, h);
      f32x4 pw0[4], pw1[4];
#pragma unroll
      for (int p = 0; p < 4; ++p) {
        const float* q = PW + p * 64 + 32 * h + 8 * g;
        pw0[p] = *(const f32x4*)q;
        pw1[p] = *(const f32x4*)(q + 4);
      }
#pragma unroll
      for (int gr = 0; gr < 4; ++gr) {
        float v[8];
        get_half(sl, m, g, gr, v);
        if (ok[gr]) {
          float* p = AF + (size_t)nat[gr] * 64 + 32 * h + 8 * g;
          *(float4*)p = make_float4(v[0], v[1], v[2], v[3]);
          *(float4*)(p + 4) = make_float4(v[4], v[5], v[6], v[7]);
        }
#pragma unroll
        for (int p = 0; p < 4; ++p)
#pragma unroll
          for (int i = 0; i < 4; ++i)
            pp[gr][p] += v[i] * pw0[p][i] + v[i + 4] * pw1[p][i];
      }
    }
    // reduce over g lanes (l^16, l^32), then lane (m,g) writes prop p=g
#pragma unroll
    for (int gr = 0; gr < 4; ++gr) {
      float r0 = pp[gr][0], r1 = pp[gr][1], r2 = pp[gr][2], r3 = pp[gr][3];
      r0 += __shfl_xor(r0, 16); r0 += __shfl_xor(r0, 32);
      r1 += __shfl_xor(r1, 16); r1 += __shfl_xor(r1, 32);
      r2 += __shfl_xor(r2, 16); r2 += __shfl_xor(r2, 32);
      r3 += __shfl_xor(r3, 16); r3 += __shfl_xor(r3, 32);
      float sel = (g == 0) ? r0 : (g == 1) ? r1 : (g == 2) ? r2 : r3;
      if (ok[gr]) PR[(size_t)nat[gr] * 4 + g] = sel + PB[g];
    }
  }
}

extern "C" void kernel_launch(void* const* d_in, const int* in_sizes, int n_in,
                              void* d_out, int out_size, void* d_ws, size_t ws_size,
                              hipStream_t stream) {
  const float* atom_fea = (const float*)d_in[0];
  const int*   nbr_idx  = (const int*)d_in[2];
  const float* ae_w   = (const float*)d_in[3];
  const float* ae_b   = (const float*)d_in[4];
  const float* msg_w1 = (const float*)d_in[7];
  const float* msg_b1 = (const float*)d_in[8];
  const float* msg_w2 = (const float*)d_in[9];
  const float* msg_b2 = (const float*)d_in[10];
  const float* upd_w1 = (const float*)d_in[11];
  const float* upd_b1 = (const float*)d_in[12];
  const float* upd_w2 = (const float*)d_in[13];
  const float* upd_b2 = (const float*)d_in[14];
  const float* fx_w1  = (const float*)d_in[15];
  const float* fx_b1  = (const float*)d_in[16];
  const float* fx_w2  = (const float*)d_in[17];
  const float* fx_b2  = (const float*)d_in[18];
  const float* prop_w = (const float*)d_in[19];
  const float* prop_b = (const float*)d_in[20];

  float* props   = (float*)d_out;
  float* af_reg  = props + (size_t)NA * 4;
  float* raw_reg = af_reg + (size_t)NA * 64;
  unsigned short* Abf = (unsigned short*)d_ws;       // [NA][64] bf16, in-place
  unsigned short* S   = Abf + (size_t)NA * 64;        // [NA][64] bf16, in-place
  unsigned short* T0  = S + (size_t)NA * 64;
  unsigned short* T1  = T0 + (size_t)NA * 64;
  unsigned short* WHp = T1 + (size_t)NA * 64;
  unsigned short* WLp = WHp + 96256;

  k_prep<<<376, 256, 0, stream>>>(ae_w, msg_w1, msg_w2, upd_w1, upd_w2,
                                  fx_w1, fx_w2, WHp, WLp);

  int ngrid = (NA + 255) / 256;   // 1172
  k_embed_st<<<ngrid, 256, 0, stream>>>(atom_fea, WHp, WLp, ae_b, msg_b1,
                                        Abf, S, T0);

  const int base0 = 6144, base1 = 6144 + 24576, base2 = 6144 + 2 * 24576;

  // layer 0: A,S in-place; T0 -> T1
  k_dense<1, 0><<<ngrid, 256, 0, stream>>>(
      Abf, S, T0, nbr_idx, WHp, WLp,
      base0 + 8192, base0 + 12288, base0 + 20480, base1,
      msg_b2, upd_b1, upd_b2, msg_b1 + 64,
      fx_b1, fx_b2, prop_w, prop_b,
      T1, nullptr, nullptr, nullptr);

  // layer 1: A,S in-place; T1 -> T0
  k_dense<1, 0><<<ngrid, 256, 0, stream>>>(
      Abf, S, T1, nbr_idx, WHp, WLp,
      base1 + 8192, base1 + 12288, base1 + 20480, base2,
      msg_b2 + 64, upd_b1 + 64, upd_b2 + 64, msg_b1 + 128,
      fx_b1, fx_b2, prop_w, prop_b,
      T0, nullptr, nullptr, nullptr);

  // layer 2 + fx: raw -> raw_reg (f32), af -> af_reg, props -> d_out
  k_dense<0, 1><<<ngrid, 256, 0, stream>>>(
      Abf, S, T0, nbr_idx, WHp, WLp,
      base2 + 8192, base2 + 12288, base2 + 20480, 0,
      msg_b2 + 128, upd_b1 + 128, upd_b2 + 128, msg_b1,
      fx_b1, fx_b2, prop_w, prop_b,
      T1, raw_reg, af_reg, props);
}

// Round 12
// 532.910 us; speedup vs baseline: 2.2232x; 1.0246x over previous
//
#include <hip/hip_runtime.h>
#include <hip/hip_bf16.h>

// AtomicScaleModule — CGCNN GNN forward, MFMA bf16 activations x split-bf16
// weights. R11 structure (gather-first, no fences, two-phase [32][69] slab,
// (256,2), bf16 A/S/T, A+S single-buffered in-place, T ping-pong).
// Delta vs R11: ALL activation operands are 2-term bf16 (weights keep hi+lo):
//   x@W ~= bf16(x)@Wh + bf16(x)@Wl  -> per-stage MFMA 96->64, mk_frag -> mk_hi
// (accuracy slack: activations already bf16 at every storage point; absmax
// was 0.5 vs threshold 2.31).
//   a = X@AE + ae_b
//   per layer: s = a@MW1[0:64]+b1 ; t = a@MW1[64:128]   (fused into producer)
//              H = sum_c relu(s + t[idx])               (gather @ head of dense)
//              agg = H@MW2 + 12*b2
//              u1 = relu(a@UW1[0:64] + agg@UW1[64:128] + ub1)
//              a' = relu(a + u1@UW2 + ub2)  (+ fused s,t of next layer)
//   af = relu(a@FX1+fb1)@FX2+fb2 ; props = af@PW^T+pb   (fused into last dense)
// nbr_fea / ne_w / ne_b dead.

constexpr int NA = 300000;

typedef short  s16x8 __attribute__((ext_vector_type(8)));
typedef float  f32x4 __attribute__((ext_vector_type(4)));

#define DEVFN static __device__ __forceinline__

DEVFN unsigned short f2bf(float x) {
  unsigned u = __float_as_uint(x);
  u += 0x7fffu + ((u >> 16) & 1u);          // RTNE
  return (unsigned short)(u >> 16);
}
DEVFN float bf2f(unsigned short h) { return __uint_as_float(((unsigned)h) << 16); }

// round 8 floats to bf16 fragment (v_cvt_pk_bf16_f32 pairs)
DEVFN s16x8 mk_hi(const float* v) {
  s16x8 hi;
#pragma unroll
  for (int i = 0; i < 8; i += 2) {
    __hip_bfloat162 h2 = __float22bfloat162_rn(make_float2(v[i], v[i + 1]));
    hi[i]     = (short)__bfloat16_as_ushort(h2.x);
    hi[i + 1] = (short)__bfloat16_as_ushort(h2.y);
  }
  return hi;
}

// 2-term MFMA: activation exact in bf16, weight split hi/lo
DEVFN f32x4 mf2(s16x8 ah, s16x8 bh, s16x8 bl, f32x4 c) {
  c = __builtin_amdgcn_mfma_f32_16x16x32_bf16(ah, bl, c, 0, 0, 0);
  c = __builtin_amdgcn_mfma_f32_16x16x32_bf16(ah, bh, c, 0, 0, 0);
  return c;
}

DEVFN void ldB(const unsigned short* __restrict__ WH, const unsigned short* __restrict__ WL,
               int seg, int kt, int ct, int CT, int l, s16x8& bh, s16x8& bl) {
  size_t o = (size_t)seg + ((size_t)((kt * CT + ct) * 64 + l)) * 8;
  bh = *(const s16x8*)(WH + o);
  bl = *(const s16x8*)(WL + o);
}

DEVFN f32x4 bias4(float bv) { f32x4 c; c[0] = bv; c[1] = bv; c[2] = bv; c[3] = bv; return c; }

// one 64x64 GEMM stage for all 4 groups: 8 B-pairs, 64 MFMA.
DEVFN void stage_mm(const unsigned short* __restrict__ WH,
                    const unsigned short* __restrict__ WL,
                    int seg, int kt0,
                    const s16x8 (&fh)[4][2],
                    int l, f32x4 (&cc)[4][4]) {
#pragma unroll
  for (int ct = 0; ct < 4; ++ct)
#pragma unroll
    for (int kt = 0; kt < 2; ++kt) {
      s16x8 bh, bl; ldB(WH, WL, seg, kt0 + kt, ct, 4, l, bh, bl);
#pragma unroll
      for (int gr = 0; gr < 4; ++gr)
        cc[gr][ct] = mf2(fh[gr][kt], bh, bl, cc[gr][ct]);
    }
}

// ---- two-phase slab transpose: half h covers features 32h..32h+31 ---------
DEVFN void put_half(float (*sl)[69], int m, int g, const f32x4 (&cc)[4][4], int h) {
#pragma unroll
  for (int gr = 0; gr < 4; ++gr)
#pragma unroll
    for (int c = 0; c < 2; ++c)
#pragma unroll
      for (int r = 0; r < 4; ++r)
        sl[16 * c + m][gr * 17 + 4 * g + r] = cc[gr][2 * h + c][r];
}
DEVFN void get_half(const float (*sl)[69], int m, int g, int gr, float* v) {
#pragma unroll
  for (int i = 0; i < 8; ++i) v[i] = sl[8 * g + i][gr * 17 + m];
}

DEVFN void trans_frags(float (*sl)[69], int m, int g, const f32x4 (&cc)[4][4],
                       s16x8 (&fh)[4][2]) {
#pragma unroll
  for (int h = 0; h < 2; ++h) {
    put_half(sl, m, g, cc, h);
#pragma unroll
    for (int gr = 0; gr < 4; ++gr) {
      float v[8];
      get_half(sl, m, g, gr, v);
      fh[gr][h] = mk_hi(v);
    }
  }
}

DEVFN void pack_store8(unsigned short* __restrict__ p, const float* v) {
  uint4 q;
  unsigned* qp = (unsigned*)&q;
#pragma unroll
  for (int i = 0; i < 4; ++i)
    qp[i] = (unsigned)f2bf(v[2 * i]) | ((unsigned)f2bf(v[2 * i + 1]) << 16);
  *(uint4*)p = q;
}

// store 64 bf16 per atom (used for S and T)
DEVFN void trans_store_bf(float (*sl)[69], int m, int g, const f32x4 (&cc)[4][4],
                          unsigned short* __restrict__ B, const int (&nat)[4], const bool (&ok)[4]) {
#pragma unroll
  for (int h = 0; h < 2; ++h) {
    put_half(sl, m, g, cc, h);
#pragma unroll
    for (int gr = 0; gr < 4; ++gr) {
      float v[8];
      get_half(sl, m, g, gr, v);
      if (ok[gr]) pack_store8(B + (size_t)nat[gr] * 64 + 32 * h + 8 * g, v);
    }
  }
}

// ---- weight pre-conversion to B-frag layout (hi/lo bf16) ------------------
// Segments (entry offsets): AE 0 (96x64); per layer base=6144+l*24576:
//   MW1 +0 (128x64), MW2 +8192 (64x64), UW1 +12288 (128x64), UW2 +20480 (64x64)
// FX1 79872 (64x128), FX2 88064 (128x64). Total 96256 entries.
__global__ __launch_bounds__(256) void k_prep(
    const float* __restrict__ ae, const float* __restrict__ mw1,
    const float* __restrict__ mw2, const float* __restrict__ uw1,
    const float* __restrict__ uw2, const float* __restrict__ fx1,
    const float* __restrict__ fx2,
    unsigned short* __restrict__ WH, unsigned short* __restrict__ WL) {
  int e = blockIdx.x * 256 + threadIdx.x;
  const float* src;
  int K, N, loc;
  if (e < 6144) { src = ae; K = 92; N = 64; loc = e; }
  else if (e < 79872) {
    int r = e - 6144;
    int lyr = r / 24576, q = r % 24576;
    size_t l64 = (size_t)lyr * 64;
    if (q < 8192)       { src = mw1 + l64 * 128; K = 128; N = 64; loc = q; }
    else if (q < 12288) { src = mw2 + l64 * 64;  K = 64;  N = 64; loc = q - 8192; }
    else if (q < 20480) { src = uw1 + l64 * 128; K = 128; N = 64; loc = q - 12288; }
    else                { src = uw2 + l64 * 64;  K = 64;  N = 64; loc = q - 20480; }
  }
  else if (e < 88064) { src = fx1; K = 64;  N = 128; loc = e - 79872; }
  else if (e < 96256) { src = fx2; K = 128; N = 64;  loc = e - 88064; }
  else return;
  int k = (N == 64) ? (loc >> 6) : (loc >> 7);
  int j = loc & (N - 1);
  float v = (k < K) ? src[(size_t)k * N + j] : 0.f;
  unsigned short h = f2bf(v);
  int CT = N >> 4;
  int lane = ((k >> 3) & 3) * 16 + (j & 15);
  int fidx = (e - loc) + (((k >> 5) * CT + (j >> 4)) * 64 + lane) * 8 + (k & 7);
  WH[fidx] = h;
  WL[fidx] = f2bf(v - bf2f(h));
}

// ---- embed + s,t of layer 0 (64 atoms per wave) ---------------------------
__global__ __launch_bounds__(256, 2) void k_embed_st(
    const float* __restrict__ X,
    const unsigned short* __restrict__ WH, const unsigned short* __restrict__ WL,
    const float* __restrict__ aeb, const float* __restrict__ b1,
    unsigned short* __restrict__ A, unsigned short* __restrict__ S,
    unsigned short* __restrict__ T) {
  __shared__ float slab[4][32][69];
  int w = threadIdx.x >> 6, l = threadIdx.x & 63, m = l & 15, g = l >> 4;
  float (*sl)[69] = slab[w];
  int nbase = blockIdx.x * 256 + w * 64;
  int nat[4]; bool ok[4];
#pragma unroll
  for (int gr = 0; gr < 4; ++gr) {
    nat[gr] = nbase + gr * 16 + m;
    ok[gr] = nat[gr] < NA;
    if (!ok[gr]) nat[gr] = NA - 1;
  }

  // a0 = X@AE + ae_b ; X fragments built per kt to bound liveness
  f32x4 ca[4][4];
#pragma unroll
  for (int gr = 0; gr < 4; ++gr)
#pragma unroll
    for (int ct = 0; ct < 4; ++ct) ca[gr][ct] = bias4(aeb[16 * ct + m]);
#pragma unroll
  for (int kt = 0; kt < 3; ++kt) {
    s16x8 xh[4];
#pragma unroll
    for (int gr = 0; gr < 4; ++gr) {
      const float* xr = X + (size_t)nat[gr] * 92;
      float v[8];
      if (kt < 2) {
        f32x4 a = *(const f32x4*)(xr + kt * 32 + g * 8);
        f32x4 b = *(const f32x4*)(xr + kt * 32 + g * 8 + 4);
        v[0]=a[0]; v[1]=a[1]; v[2]=a[2]; v[3]=a[3]; v[4]=b[0]; v[5]=b[1]; v[6]=b[2]; v[7]=b[3];
      } else if (g < 3) {
        f32x4 a = *(const f32x4*)(xr + 64 + g * 8);
        f32x4 b = *(const f32x4*)(xr + 64 + g * 8 + 4);
        v[0]=a[0]; v[1]=a[1]; v[2]=a[2]; v[3]=a[3]; v[4]=b[0]; v[5]=b[1]; v[6]=b[2]; v[7]=b[3];
      } else {
        f32x4 a = *(const f32x4*)(xr + 88);   // 88..91 valid, 92..95 pad
        v[0]=a[0]; v[1]=a[1]; v[2]=a[2]; v[3]=a[3]; v[4]=0.f; v[5]=0.f; v[6]=0.f; v[7]=0.f;
      }
      xh[gr] = mk_hi(v);
    }
#pragma unroll
    for (int ct = 0; ct < 4; ++ct) {
      s16x8 bh, bl; ldB(WH, WL, 0, kt, ct, 4, l, bh, bl);
#pragma unroll
      for (int gr = 0; gr < 4; ++gr)
        ca[gr][ct] = mf2(xh[gr], bh, bl, ca[gr][ct]);
    }
  }

  // transpose a0: store A (bf16) + build fragments, one read pass
  s16x8 ah[4][2];
#pragma unroll
  for (int h = 0; h < 2; ++h) {
    put_half(sl, m, g, ca, h);
#pragma unroll
    for (int gr = 0; gr < 4; ++gr) {
      float v[8];
      get_half(sl, m, g, gr, v);
      if (ok[gr]) pack_store8(A + (size_t)nat[gr] * 64 + 32 * h + 8 * g, v);
      ah[gr][h] = mk_hi(v);
    }
  }

  // s = a0@MW1[0:64] + b1  (stored bf16)
  f32x4 cs[4][4];
#pragma unroll
  for (int gr = 0; gr < 4; ++gr)
#pragma unroll
    for (int ct = 0; ct < 4; ++ct) cs[gr][ct] = bias4(b1[16 * ct + m]);
  stage_mm(WH, WL, 6144, 0, ah, l, cs);
  trans_store_bf(sl, m, g, cs, S, nat, ok);

  // t = a0@MW1[64:128]
  f32x4 cT[4][4];
#pragma unroll
  for (int gr = 0; gr < 4; ++gr)
#pragma unroll
    for (int ct = 0; ct < 4; ++ct) cT[gr][ct] = bias4(0.f);
  stage_mm(WH, WL, 6144, 2, ah, l, cT);
  trans_store_bf(sl, m, g, cT, T, nat, ok);
}

// ---- fused: gather + dense chain (+ next-layer s,t | + fx tail) -----------
// A and S are updated IN-PLACE (own-row read-then-write, race-free).
template <int HAS_NEXT, int HAS_FX>
__global__ __launch_bounds__(256, 2) void k_dense(
    unsigned short* __restrict__ A, unsigned short* __restrict__ S,
    const unsigned short* __restrict__ T, const int* __restrict__ IDX,
    const unsigned short* __restrict__ WH, const unsigned short* __restrict__ WL,
    int segW2, int segU1, int segU2, int segWn,
    const float* __restrict__ b2, const float* __restrict__ ub1,
    const float* __restrict__ ub2, const float* __restrict__ bn,
    const float* __restrict__ fb1, const float* __restrict__ fb2,
    const float* __restrict__ PW, const float* __restrict__ PB,
    unsigned short* __restrict__ Tout,
    float* __restrict__ RawOut, float* __restrict__ AF, float* __restrict__ PR) {
  __shared__ float slab[4][32][69];
  int w = threadIdx.x >> 6, l = threadIdx.x & 63, m = l & 15, g = l >> 4;
  float (*sl)[69] = slab[w];
  int nbase = blockIdx.x * 256 + w * 64;
  int nat[4]; bool ok[4];
#pragma unroll
  for (int gr = 0; gr < 4; ++gr) {
    nat[gr] = nbase + gr * 16 + m;
    ok[gr] = nat[gr] < NA;
    if (!ok[gr]) nat[gr] = NA - 1;
  }

  // gather FIRST: H = sum_c relu(s + t[idx]); loads issue at kernel entry.
  s16x8 hh[4][2];
#pragma unroll
  for (int gr = 0; gr < 4; ++gr) {
    const int* ip = IDX + (size_t)nat[gr] * 12;
    int4 i0 = *(const int4*)ip;
    int4 i1 = *(const int4*)(ip + 4);
    int4 i2 = *(const int4*)(ip + 8);
    int idxs[12] = {i0.x, i0.y, i0.z, i0.w, i1.x, i1.y, i1.z, i1.w,
                    i2.x, i2.y, i2.z, i2.w};
#pragma unroll
    for (int kt = 0; kt < 2; ++kt) {
      int f0 = 32 * kt + 8 * g;
      uint4 sv4 = *(const uint4*)(S + (size_t)nat[gr] * 64 + f0);
      float sv[8] = {
        bf2f((unsigned short)(sv4.x & 0xffff)), bf2f((unsigned short)(sv4.x >> 16)),
        bf2f((unsigned short)(sv4.y & 0xffff)), bf2f((unsigned short)(sv4.y >> 16)),
        bf2f((unsigned short)(sv4.z & 0xffff)), bf2f((unsigned short)(sv4.z >> 16)),
        bf2f((unsigned short)(sv4.w & 0xffff)), bf2f((unsigned short)(sv4.w >> 16))};
      float ha[8] = {0, 0, 0, 0, 0, 0, 0, 0};
#pragma unroll
      for (int c = 0; c < 12; ++c) {
        uint4 tv = *(const uint4*)(T + (size_t)idxs[c] * 64 + f0);
        ha[0] += fmaxf(sv[0] + bf2f((unsigned short)(tv.x & 0xffff)), 0.f);
        ha[1] += fmaxf(sv[1] + bf2f((unsigned short)(tv.x >> 16)), 0.f);
        ha[2] += fmaxf(sv[2] + bf2f((unsigned short)(tv.y & 0xffff)), 0.f);
        ha[3] += fmaxf(sv[3] + bf2f((unsigned short)(tv.y >> 16)), 0.f);
        ha[4] += fmaxf(sv[4] + bf2f((unsigned short)(tv.z & 0xffff)), 0.f);
        ha[5] += fmaxf(sv[5] + bf2f((unsigned short)(tv.z >> 16)), 0.f);
        ha[6] += fmaxf(sv[6] + bf2f((unsigned short)(tv.w & 0xffff)), 0.f);
        ha[7] += fmaxf(sv[7] + bf2f((unsigned short)(tv.w >> 16)), 0.f);
      }
      hh[gr][kt] = mk_hi(ha);
    }
  }

  // agg = H@W2 + 12*b2
  f32x4 cg[4][4];
#pragma unroll
  for (int gr = 0; gr < 4; ++gr)
#pragma unroll
    for (int ct = 0; ct < 4; ++ct) cg[gr][ct] = bias4(12.f * b2[16 * ct + m]);
  stage_mm(WH, WL, segW2, 0, hh, l, cg);

  // u1: a-part (bf16 A, straight loads), then agg-part
  f32x4 cu[4][4];
#pragma unroll
  for (int gr = 0; gr < 4; ++gr)
#pragma unroll
    for (int ct = 0; ct < 4; ++ct) cu[gr][ct] = bias4(ub1[16 * ct + m]);
  {
    s16x8 arh[4][2];
#pragma unroll
    for (int gr = 0; gr < 4; ++gr)
#pragma unroll
      for (int kt = 0; kt < 2; ++kt)
        arh[gr][kt] = *(const s16x8*)(A + (size_t)nat[gr] * 64 + kt * 32 + g * 8);
    stage_mm(WH, WL, segU1, 0, arh, l, cu);
  }
  {
    s16x8 qh[4][2];
    trans_frags(sl, m, g, cg, qh);
    stage_mm(WH, WL, segU1, 2, qh, l, cu);
  }
#pragma unroll
  for (int gr = 0; gr < 4; ++gr)
#pragma unroll
    for (int ct = 0; ct < 4; ++ct)
#pragma unroll
      for (int r = 0; r < 4; ++r) cu[gr][ct][r] = fmaxf(cu[gr][ct][r], 0.f);

  // upd = u1@U2 + ub2
  f32x4 cd[4][4];
#pragma unroll
  for (int gr = 0; gr < 4; ++gr)
#pragma unroll
    for (int ct = 0; ct < 4; ++ct) cd[gr][ct] = bias4(ub2[16 * ct + m]);
  {
    s16x8 uh[4][2];
    trans_frags(sl, m, g, cu, uh);
    stage_mm(WH, WL, segU2, 0, uh, l, cd);
  }

  // a' = relu(a + upd): transpose, residual re-read (bf16, L2-hot),
  // store (bf16 in-place | f32 raw), fragments for next stages.
  s16x8 anh[4][2];
#pragma unroll
  for (int h = 0; h < 2; ++h) {
    put_half(sl, m, g, cd, h);
#pragma unroll
    for (int gr = 0; gr < 4; ++gr) {
      float v[8];
      get_half(sl, m, g, gr, v);
      uint4 au = *(const uint4*)(A + (size_t)nat[gr] * 64 + 32 * h + 8 * g);
      float av[8] = {
        bf2f((unsigned short)(au.x & 0xffff)), bf2f((unsigned short)(au.x >> 16)),
        bf2f((unsigned short)(au.y & 0xffff)), bf2f((unsigned short)(au.y >> 16)),
        bf2f((unsigned short)(au.z & 0xffff)), bf2f((unsigned short)(au.z >> 16)),
        bf2f((unsigned short)(au.w & 0xffff)), bf2f((unsigned short)(au.w >> 16))};
#pragma unroll
      for (int i = 0; i < 8; ++i) v[i] = fmaxf(v[i] + av[i], 0.f);
      if constexpr (HAS_FX) {
        if (ok[gr]) {
          float* p = RawOut + (size_t)nat[gr] * 64 + 32 * h + 8 * g;
          *(float4*)p = make_float4(v[0], v[1], v[2], v[3]);
          *(float4*)(p + 4) = make_float4(v[4], v[5], v[6], v[7]);
        }
      } else {
        if (ok[gr]) pack_store8(A + (size_t)nat[gr] * 64 + 32 * h + 8 * g, v);
      }
      if constexpr (HAS_NEXT || HAS_FX) anh[gr][h] = mk_hi(v);
    }
  }

  if constexpr (HAS_NEXT) {
    // s_next (bf16, in-place over S)
    f32x4 cs[4][4];
#pragma unroll
    for (int gr = 0; gr < 4; ++gr)
#pragma unroll
      for (int ct = 0; ct < 4; ++ct) cs[gr][ct] = bias4(bn[16 * ct + m]);
    stage_mm(WH, WL, segWn, 0, anh, l, cs);
    trans_store_bf(sl, m, g, cs, S, nat, ok);

    // t_next (bf16, ping-pong buffer)
    f32x4 cT[4][4];
#pragma unroll
    for (int gr = 0; gr < 4; ++gr)
#pragma unroll
      for (int ct = 0; ct < 4; ++ct) cT[gr][ct] = bias4(0.f);
    stage_mm(WH, WL, segWn, 2, anh, l, cT);
    trans_store_bf(sl, m, g, cT, Tout, nat, ok);
  }

  if constexpr (HAS_FX) {
    // af = relu(raw@FX1+fb1)@FX2+fb2, hidden 128 in two 64-col rounds
    f32x4 cf[4][4];
#pragma unroll
    for (int gr = 0; gr < 4; ++gr)
#pragma unroll
      for (int ct = 0; ct < 4; ++ct) cf[gr][ct] = bias4(fb2[16 * ct + m]);

#pragma unroll
    for (int hr = 0; hr < 2; ++hr) {
      f32x4 chh[4][4];
#pragma unroll
      for (int gr = 0; gr < 4; ++gr)
#pragma unroll
        for (int ct = 0; ct < 4; ++ct)
          chh[gr][ct] = bias4(fb1[16 * (4 * hr + ct) + m]);
#pragma unroll
      for (int ct = 0; ct < 4; ++ct)
#pragma unroll
        for (int kt = 0; kt < 2; ++kt) {
          s16x8 bh, bl; ldB(WH, WL, 79872, kt, 4 * hr + ct, 8, l, bh, bl);
#pragma unroll
          for (int gr = 0; gr < 4; ++gr)
            chh[gr][ct] = mf2(anh[gr][kt], bh, bl, chh[gr][ct]);
        }
#pragma unroll
      for (int gr = 0; gr < 4; ++gr)
#pragma unroll
        for (int ct = 0; ct < 4; ++ct)
#pragma unroll
          for (int r = 0; r < 4; ++r) chh[gr][ct][r] = fmaxf(chh[gr][ct][r], 0.f);

      s16x8 hfh[4][2];
      trans_frags(sl, m, g, chh, hfh);
      stage_mm(WH, WL, 88064, 2 * hr, hfh, l, cf);
    }

    // AF store + props partials in the same A-layout pass
    float pp[4][4];
#pragma unroll
    for (int gr = 0; gr < 4; ++gr)
#pragma unroll
      for (int p = 0; p < 4; ++p) pp[gr][p] = 0.f;
#pragma unroll
    for (int h = 0; h < 2; ++h) {
      put_half(sl, m, g, cf, h);
      f32x4 pw0[4], pw1[4];
#pragma unroll
      for (int p = 0; p < 4; ++p) {
        const float* q = PW + p * 64 + 32 * h + 8 * g;
        pw0[p] = *(const f32x4*)q;
        pw1[p] = *(const f32x4*)(q + 4);
      }
#pragma unroll
      for (int gr = 0; gr < 4; ++gr) {
        float v[8];
        get_half(sl, m, g, gr, v);
        if (ok[gr]) {
          float* p = AF + (size_t)nat[gr] * 64 + 32 * h + 8 * g;
          *(float4*)p = make_float4(v[0], v[1], v[2], v[3]);
          *(float4*)(p + 4) = make_float4(v[4], v[5], v[6], v[7]);
        }
#pragma unroll
        for (int p = 0; p < 4; ++p)
#pragma unroll
          for (int i = 0; i < 4; ++i)
            pp[gr][p] += v[i] * pw0[p][i] + v[i + 4] * pw1[p][i];
      }
    }
    // reduce over g lanes (l^16, l^32), then lane (m,g) writes prop p=g
#pragma unroll
    for (int gr = 0; gr < 4; ++gr) {
      float r0 = pp[gr][0], r1 = pp[gr][1], r2 = pp[gr][2], r3 = pp[gr][3];
      r0 += __shfl_xor(r0, 16); r0 += __shfl_xor(r0, 32);
      r1 += __shfl_xor(r1, 16); r1 += __shfl_xor(r1, 32);
      r2 += __shfl_xor(r2, 16); r2 += __shfl_xor(r2, 32);
      r3 += __shfl_xor(r3, 16); r3 += __shfl_xor(r3, 32);
      float sel = (g == 0) ? r0 : (g == 1) ? r1 : (g == 2) ? r2 : r3;
      if (ok[gr]) PR[(size_t)nat[gr] * 4 + g] = sel + PB[g];
    }
  }
}

extern "C" void kernel_launch(void* const* d_in, const int* in_sizes, int n_in,
                              void* d_out, int out_size, void* d_ws, size_t ws_size,
                              hipStream_t stream) {
  const float* atom_fea = (const float*)d_in[0];
  const int*   nbr_idx  = (const int*)d_in[2];
  const float* ae_w   = (const float*)d_in[3];
  const float* ae_b   = (const float*)d_in[4];
  const float* msg_w1 = (const float*)d_in[7];
  const float* msg_b1 = (const float*)d_in[8];
  const float* msg_w2 = (const float*)d_in[9];
  const float* msg_b2 = (const float*)d_in[10];
  const float* upd_w1 = (const float*)d_in[11];
  const float* upd_b1 = (const float*)d_in[12];
  const float* upd_w2 = (const float*)d_in[13];
  const float* upd_b2 = (const float*)d_in[14];
  const float* fx_w1  = (const float*)d_in[15];
  const float* fx_b1  = (const float*)d_in[16];
  const float* fx_w2  = (const float*)d_in[17];
  const float* fx_b2  = (const float*)d_in[18];
  const float* prop_w = (const float*)d_in[19];
  const float* prop_b = (const float*)d_in[20];

  float* props   = (float*)d_out;
  float* af_reg  = props + (size_t)NA * 4;
  float* raw_reg = af_reg + (size_t)NA * 64;
  unsigned short* Abf = (unsigned short*)d_ws;        // [NA][64] bf16, in-place
  unsigned short* S   = Abf + (size_t)NA * 64;        // [NA][64] bf16, in-place
  unsigned short* T0  = S + (size_t)NA * 64;
  unsigned short* T1  = T0 + (size_t)NA * 64;
  unsigned short* WHp = T1 + (size_t)NA * 64;
  unsigned short* WLp = WHp + 96256;

  k_prep<<<376, 256, 0, stream>>>(ae_w, msg_w1, msg_w2, upd_w1, upd_w2,
                                  fx_w1, fx_w2, WHp, WLp);

  int ngrid = (NA + 255) / 256;   // 1172
  k_embed_st<<<ngrid, 256, 0, stream>>>(atom_fea, WHp, WLp, ae_b, msg_b1,
                                        Abf, S, T0);

  const int base0 = 6144, base1 = 6144 + 24576, base2 = 6144 + 2 * 24576;

  // layer 0: A,S in-place; T0 -> T1
  k_dense<1, 0><<<ngrid, 256, 0, stream>>>(
      Abf, S, T0, nbr_idx, WHp, WLp,
      base0 + 8192, base0 + 12288, base0 + 20480, base1,
      msg_b2, upd_b1, upd_b2, msg_b1 + 64,
      fx_b1, fx_b2, prop_w, prop_b,
      T1, nullptr, nullptr, nullptr);

  // layer 1: A,S in-place; T1 -> T0
  k_dense<1, 0><<<ngrid, 256, 0, stream>>>(
      Abf, S, T1, nbr_idx, WHp, WLp,
      base1 + 8192, base1 + 12288, base1 + 20480, base2,
      msg_b2 + 64, upd_b1 + 64, upd_b2 + 64, msg_b1 + 128,
      fx_b1, fx_b2, prop_w, prop_b,
      T0, nullptr, nullptr, nullptr);

  // layer 2 + fx: raw -> raw_reg (f32), af -> af_reg, props -> d_out
  k_dense<0, 1><<<ngrid, 256, 0, stream>>>(
      Abf, S, T0, nbr_idx, WHp, WLp,
      base2 + 8192, base2 + 12288, base2 + 20480, 0,
      msg_b2 + 128, upd_b1 + 128, upd_b2 + 128, msg_b1,
      fx_b1, fx_b2, prop_w, prop_b,
      T1, raw_reg, af_reg, props);
}

// Round 14
// 509.799 us; speedup vs baseline: 2.3240x; 1.0453x over previous
//
#include <hip/hip_runtime.h>
#include <hip/hip_bf16.h>

// AtomicScaleModule — CGCNN GNN forward, MFMA bf16 activations x split-bf16
// weights. R12 structure (gather-first, no fences, (256,2), bf16 A/S/T,
// A+S single-buffered in-place, T ping-pong).
// Delta vs R12: bf16 transpose slab (u16 [32][74], group stride 18,
// 18.9 KB/block), rounded once on entry.
// R13 post-mortem: entry writes MUST be u16-typed (not u32 type-punned) —
// clang TBAA treats unsigned/unsigned short as non-aliasing and reorders
// the u16 reads above the u32 writes -> garbage (absmax 21). All slab
// accesses are now u16; clang merges adjacent u16 stores itself.
//   a = X@AE + ae_b
//   per layer: s = a@MW1[0:64]+b1 ; t = a@MW1[64:128]   (fused into producer)
//              H = sum_c relu(s + t[idx])               (gather @ head of dense)
//              agg = H@MW2 + 12*b2
//              u1 = relu(a@UW1[0:64] + agg@UW1[64:128] + ub1)
//              a' = relu(a + u1@UW2 + ub2)  (+ fused s,t of next layer)
//   af = relu(a@FX1+fb1)@FX2+fb2 ; props = af@PW^T+pb   (fused into last dense)
// nbr_fea / ne_w / ne_b dead.

constexpr int NA = 300000;
constexpr int SCOL = 74;   // u16 cols: 4 groups x 18 (16 atoms + 2 pad), row 148B

typedef short          s16x8 __attribute__((ext_vector_type(8)));
typedef float          f32x4 __attribute__((ext_vector_type(4)));
typedef unsigned short u16;

#define DEVFN static __device__ __forceinline__

DEVFN u16 f2bf(float x) {
  unsigned u = __float_as_uint(x);
  u += 0x7fffu + ((u >> 16) & 1u);          // RTNE
  return (u16)(u >> 16);
}
DEVFN float bf2f(u16 h) { return __uint_as_float(((unsigned)h) << 16); }

// round 8 floats to bf16 fragment (v_cvt_pk_bf16_f32 pairs)
DEVFN s16x8 mk_hi(const float* v) {
  s16x8 hi;
#pragma unroll
  for (int i = 0; i < 8; i += 2) {
    __hip_bfloat162 h2 = __float22bfloat162_rn(make_float2(v[i], v[i + 1]));
    hi[i]     = (short)__bfloat16_as_ushort(h2.x);
    hi[i + 1] = (short)__bfloat16_as_ushort(h2.y);
  }
  return hi;
}

// 2-term MFMA: activation exact in bf16, weight split hi/lo
DEVFN f32x4 mf2(s16x8 ah, s16x8 bh, s16x8 bl, f32x4 c) {
  c = __builtin_amdgcn_mfma_f32_16x16x32_bf16(ah, bl, c, 0, 0, 0);
  c = __builtin_amdgcn_mfma_f32_16x16x32_bf16(ah, bh, c, 0, 0, 0);
  return c;
}

DEVFN void ldB(const u16* __restrict__ WH, const u16* __restrict__ WL,
               int seg, int kt, int ct, int CT, int l, s16x8& bh, s16x8& bl) {
  size_t o = (size_t)seg + ((size_t)((kt * CT + ct) * 64 + l)) * 8;
  bh = *(const s16x8*)(WH + o);
  bl = *(const s16x8*)(WL + o);
}

DEVFN f32x4 bias4(float bv) { f32x4 c; c[0] = bv; c[1] = bv; c[2] = bv; c[3] = bv; return c; }

// one 64x64 GEMM stage for all 4 groups: 8 B-pairs, 64 MFMA.
DEVFN void stage_mm(const u16* __restrict__ WH, const u16* __restrict__ WL,
                    int seg, int kt0, const s16x8 (&fh)[4][2],
                    int l, f32x4 (&cc)[4][4]) {
#pragma unroll
  for (int ct = 0; ct < 4; ++ct)
#pragma unroll
    for (int kt = 0; kt < 2; ++kt) {
      s16x8 bh, bl; ldB(WH, WL, seg, kt0 + kt, ct, 4, l, bh, bl);
#pragma unroll
      for (int gr = 0; gr < 4; ++gr)
        cc[gr][ct] = mf2(fh[gr][kt], bh, bl, cc[gr][ct]);
    }
}

// ---- bf16 slab transpose: half h covers features 32h..32h+31 --------------
// put: C value (row=4g+r, col-atom=16ct+m) of group gr, rounded to bf16, at
//      sl[16c+m][gr*18 + 4g+r]  — u16-typed stores ONLY (TBAA, see header).
// get: fragment element i (feature 32h+8g+i) of atom (gr,m) = sl[8g+i][gr*18+m].
DEVFN void put_half_bf(u16 (*sl)[SCOL], int m, int g, const f32x4 (&cc)[4][4], int h) {
#pragma unroll
  for (int gr = 0; gr < 4; ++gr)
#pragma unroll
    for (int c = 0; c < 2; ++c) {
      f32x4 v = cc[gr][2 * h + c];
      __hip_bfloat162 p0 = __float22bfloat162_rn(make_float2(v[0], v[1]));
      __hip_bfloat162 p1 = __float22bfloat162_rn(make_float2(v[2], v[3]));
      u16* p = &sl[16 * c + m][gr * 18 + 4 * g];
      p[0] = __bfloat16_as_ushort(p0.x);
      p[1] = __bfloat16_as_ushort(p0.y);
      p[2] = __bfloat16_as_ushort(p1.x);
      p[3] = __bfloat16_as_ushort(p1.y);
    }
}
DEVFN s16x8 get_frag(const u16 (*sl)[SCOL], int m, int g, int gr) {
  s16x8 f;
#pragma unroll
  for (int i = 0; i < 8; ++i) f[i] = (short)sl[8 * g + i][gr * 18 + m];
  return f;
}
DEVFN void get_half_f32(const u16 (*sl)[SCOL], int m, int g, int gr, float* v) {
#pragma unroll
  for (int i = 0; i < 8; ++i) v[i] = bf2f(sl[8 * g + i][gr * 18 + m]);
}

DEVFN void trans_frags(u16 (*sl)[SCOL], int m, int g, const f32x4 (&cc)[4][4],
                       s16x8 (&fh)[4][2]) {
#pragma unroll
  for (int h = 0; h < 2; ++h) {
    put_half_bf(sl, m, g, cc, h);
#pragma unroll
    for (int gr = 0; gr < 4; ++gr) fh[gr][h] = get_frag(sl, m, g, gr);
  }
}

// store 64 bf16 per atom (S / T / A): u16 reads + shift-or packs, no cvt
DEVFN void trans_store_bf(u16 (*sl)[SCOL], int m, int g, const f32x4 (&cc)[4][4],
                          u16* __restrict__ B, const int (&nat)[4], const bool (&ok)[4]) {
#pragma unroll
  for (int h = 0; h < 2; ++h) {
    put_half_bf(sl, m, g, cc, h);
#pragma unroll
    for (int gr = 0; gr < 4; ++gr) {
      if (!ok[gr]) continue;
      int col = gr * 18 + m;
      uint4 q;
      unsigned* qp = (unsigned*)&q;
#pragma unroll
      for (int j = 0; j < 4; ++j)
        qp[j] = (unsigned)sl[8 * g + 2 * j][col] | ((unsigned)sl[8 * g + 2 * j + 1][col] << 16);
      *(uint4*)(B + (size_t)nat[gr] * 64 + 32 * h + 8 * g) = q;
    }
  }
}

DEVFN void pack_store8(u16* __restrict__ p, const float* v) {
  uint4 q;
  unsigned* qp = (unsigned*)&q;
#pragma unroll
  for (int i = 0; i < 4; ++i)
    qp[i] = (unsigned)f2bf(v[2 * i]) | ((unsigned)f2bf(v[2 * i + 1]) << 16);
  *(uint4*)p = q;
}

// ---- weight pre-conversion to B-frag layout (hi/lo bf16) ------------------
// Segments (entry offsets): AE 0 (96x64); per layer base=6144+l*24576:
//   MW1 +0 (128x64), MW2 +8192 (64x64), UW1 +12288 (128x64), UW2 +20480 (64x64)
// FX1 79872 (64x128), FX2 88064 (128x64). Total 96256 entries.
__global__ __launch_bounds__(256) void k_prep(
    const float* __restrict__ ae, const float* __restrict__ mw1,
    const float* __restrict__ mw2, const float* __restrict__ uw1,
    const float* __restrict__ uw2, const float* __restrict__ fx1,
    const float* __restrict__ fx2,
    u16* __restrict__ WH, u16* __restrict__ WL) {
  int e = blockIdx.x * 256 + threadIdx.x;
  const float* src;
  int K, N, loc;
  if (e < 6144) { src = ae; K = 92; N = 64; loc = e; }
  else if (e < 79872) {
    int r = e - 6144;
    int lyr = r / 24576, q = r % 24576;
    size_t l64 = (size_t)lyr * 64;
    if (q < 8192)       { src = mw1 + l64 * 128; K = 128; N = 64; loc = q; }
    else if (q < 12288) { src = mw2 + l64 * 64;  K = 64;  N = 64; loc = q - 8192; }
    else if (q < 20480) { src = uw1 + l64 * 128; K = 128; N = 64; loc = q - 12288; }
    else                { src = uw2 + l64 * 64;  K = 64;  N = 64; loc = q - 20480; }
  }
  else if (e < 88064) { src = fx1; K = 64;  N = 128; loc = e - 79872; }
  else if (e < 96256) { src = fx2; K = 128; N = 64;  loc = e - 88064; }
  else return;
  int k = (N == 64) ? (loc >> 6) : (loc >> 7);
  int j = loc & (N - 1);
  float v = (k < K) ? src[(size_t)k * N + j] : 0.f;
  u16 h = f2bf(v);
  int CT = N >> 4;
  int lane = ((k >> 3) & 3) * 16 + (j & 15);
  int fidx = (e - loc) + (((k >> 5) * CT + (j >> 4)) * 64 + lane) * 8 + (k & 7);
  WH[fidx] = h;
  WL[fidx] = f2bf(v - bf2f(h));
}

// ---- embed + s,t of layer 0 (64 atoms per wave) ---------------------------
__global__ __launch_bounds__(256, 2) void k_embed_st(
    const float* __restrict__ X,
    const u16* __restrict__ WH, const u16* __restrict__ WL,
    const float* __restrict__ aeb, const float* __restrict__ b1,
    u16* __restrict__ A, u16* __restrict__ S, u16* __restrict__ T) {
  __shared__ u16 slab[4][32][SCOL];
  int w = threadIdx.x >> 6, l = threadIdx.x & 63, m = l & 15, g = l >> 4;
  u16 (*sl)[SCOL] = slab[w];
  int nbase = blockIdx.x * 256 + w * 64;
  int nat[4]; bool ok[4];
#pragma unroll
  for (int gr = 0; gr < 4; ++gr) {
    nat[gr] = nbase + gr * 16 + m;
    ok[gr] = nat[gr] < NA;
    if (!ok[gr]) nat[gr] = NA - 1;
  }

  // a0 = X@AE + ae_b ; X fragments built per kt to bound liveness
  f32x4 ca[4][4];
#pragma unroll
  for (int gr = 0; gr < 4; ++gr)
#pragma unroll
    for (int ct = 0; ct < 4; ++ct) ca[gr][ct] = bias4(aeb[16 * ct + m]);
#pragma unroll
  for (int kt = 0; kt < 3; ++kt) {
    s16x8 xh[4];
#pragma unroll
    for (int gr = 0; gr < 4; ++gr) {
      const float* xr = X + (size_t)nat[gr] * 92;
      float v[8];
      if (kt < 2) {
        f32x4 a = *(const f32x4*)(xr + kt * 32 + g * 8);
        f32x4 b = *(const f32x4*)(xr + kt * 32 + g * 8 + 4);
        v[0]=a[0]; v[1]=a[1]; v[2]=a[2]; v[3]=a[3]; v[4]=b[0]; v[5]=b[1]; v[6]=b[2]; v[7]=b[3];
      } else if (g < 3) {
        f32x4 a = *(const f32x4*)(xr + 64 + g * 8);
        f32x4 b = *(const f32x4*)(xr + 64 + g * 8 + 4);
        v[0]=a[0]; v[1]=a[1]; v[2]=a[2]; v[3]=a[3]; v[4]=b[0]; v[5]=b[1]; v[6]=b[2]; v[7]=b[3];
      } else {
        f32x4 a = *(const f32x4*)(xr + 88);   // 88..91 valid, 92..95 pad
        v[0]=a[0]; v[1]=a[1]; v[2]=a[2]; v[3]=a[3]; v[4]=0.f; v[5]=0.f; v[6]=0.f; v[7]=0.f;
      }
      xh[gr] = mk_hi(v);
    }
#pragma unroll
    for (int ct = 0; ct < 4; ++ct) {
      s16x8 bh, bl; ldB(WH, WL, 0, kt, ct, 4, l, bh, bl);
#pragma unroll
      for (int gr = 0; gr < 4; ++gr)
        ca[gr][ct] = mf2(xh[gr], bh, bl, ca[gr][ct]);
    }
  }

  // transpose a0: store A (bf16) + build fragments from the same u16 reads
  s16x8 ah[4][2];
#pragma unroll
  for (int h = 0; h < 2; ++h) {
    put_half_bf(sl, m, g, ca, h);
#pragma unroll
    for (int gr = 0; gr < 4; ++gr) {
      int col = gr * 18 + m;
      u16 t8[8];
#pragma unroll
      for (int i = 0; i < 8; ++i) t8[i] = sl[8 * g + i][col];
      if (ok[gr]) {
        uint4 q;
        unsigned* qp = (unsigned*)&q;
#pragma unroll
        for (int j = 0; j < 4; ++j)
          qp[j] = (unsigned)t8[2 * j] | ((unsigned)t8[2 * j + 1] << 16);
        *(uint4*)(A + (size_t)nat[gr] * 64 + 32 * h + 8 * g) = q;
      }
      s16x8 f;
#pragma unroll
      for (int i = 0; i < 8; ++i) f[i] = (short)t8[i];
      ah[gr][h] = f;
    }
  }

  // s = a0@MW1[0:64] + b1  (stored bf16)
  f32x4 cs[4][4];
#pragma unroll
  for (int gr = 0; gr < 4; ++gr)
#pragma unroll
    for (int ct = 0; ct < 4; ++ct) cs[gr][ct] = bias4(b1[16 * ct + m]);
  stage_mm(WH, WL, 6144, 0, ah, l, cs);
  trans_store_bf(sl, m, g, cs, S, nat, ok);

  // t = a0@MW1[64:128]
  f32x4 cT[4][4];
#pragma unroll
  for (int gr = 0; gr < 4; ++gr)
#pragma unroll
    for (int ct = 0; ct < 4; ++ct) cT[gr][ct] = bias4(0.f);
  stage_mm(WH, WL, 6144, 2, ah, l, cT);
  trans_store_bf(sl, m, g, cT, T, nat, ok);
}

// ---- fused: gather + dense chain (+ next-layer s,t | + fx tail) -----------
// A and S are updated IN-PLACE (own-row read-then-write, race-free).
template <int HAS_NEXT, int HAS_FX>
__global__ __launch_bounds__(256, 2) void k_dense(
    u16* __restrict__ A, u16* __restrict__ S,
    const u16* __restrict__ T, const int* __restrict__ IDX,
    const u16* __restrict__ WH, const u16* __restrict__ WL,
    int segW2, int segU1, int segU2, int segWn,
    const float* __restrict__ b2, const float* __restrict__ ub1,
    const float* __restrict__ ub2, const float* __restrict__ bn,
    const float* __restrict__ fb1, const float* __restrict__ fb2,
    const float* __restrict__ PW, const float* __restrict__ PB,
    u16* __restrict__ Tout,
    float* __restrict__ RawOut, float* __restrict__ AF, float* __restrict__ PR) {
  __shared__ u16 slab[4][32][SCOL];
  int w = threadIdx.x >> 6, l = threadIdx.x & 63, m = l & 15, g = l >> 4;
  u16 (*sl)[SCOL] = slab[w];
  int nbase = blockIdx.x * 256 + w * 64;
  int nat[4]; bool ok[4];
#pragma unroll
  for (int gr = 0; gr < 4; ++gr) {
    nat[gr] = nbase + gr * 16 + m;
    ok[gr] = nat[gr] < NA;
    if (!ok[gr]) nat[gr] = NA - 1;
  }

  // gather FIRST: H = sum_c relu(s + t[idx]); loads issue at kernel entry.
  s16x8 hh[4][2];
#pragma unroll
  for (int gr = 0; gr < 4; ++gr) {
    const int* ip = IDX + (size_t)nat[gr] * 12;
    int4 i0 = *(const int4*)ip;
    int4 i1 = *(const int4*)(ip + 4);
    int4 i2 = *(const int4*)(ip + 8);
    int idxs[12] = {i0.x, i0.y, i0.z, i0.w, i1.x, i1.y, i1.z, i1.w,
                    i2.x, i2.y, i2.z, i2.w};
#pragma unroll
    for (int kt = 0; kt < 2; ++kt) {
      int f0 = 32 * kt + 8 * g;
      uint4 sv4 = *(const uint4*)(S + (size_t)nat[gr] * 64 + f0);
      float sv[8] = {
        bf2f((u16)(sv4.x & 0xffff)), bf2f((u16)(sv4.x >> 16)),
        bf2f((u16)(sv4.y & 0xffff)), bf2f((u16)(sv4.y >> 16)),
        bf2f((u16)(sv4.z & 0xffff)), bf2f((u16)(sv4.z >> 16)),
        bf2f((u16)(sv4.w & 0xffff)), bf2f((u16)(sv4.w >> 16))};
      float ha[8] = {0, 0, 0, 0, 0, 0, 0, 0};
#pragma unroll
      for (int c = 0; c < 12; ++c) {
        uint4 tv = *(const uint4*)(T + (size_t)idxs[c] * 64 + f0);
        ha[0] += fmaxf(sv[0] + bf2f((u16)(tv.x & 0xffff)), 0.f);
        ha[1] += fmaxf(sv[1] + bf2f((u16)(tv.x >> 16)), 0.f);
        ha[2] += fmaxf(sv[2] + bf2f((u16)(tv.y & 0xffff)), 0.f);
        ha[3] += fmaxf(sv[3] + bf2f((u16)(tv.y >> 16)), 0.f);
        ha[4] += fmaxf(sv[4] + bf2f((u16)(tv.z & 0xffff)), 0.f);
        ha[5] += fmaxf(sv[5] + bf2f((u16)(tv.z >> 16)), 0.f);
        ha[6] += fmaxf(sv[6] + bf2f((u16)(tv.w & 0xffff)), 0.f);
        ha[7] += fmaxf(sv[7] + bf2f((u16)(tv.w >> 16)), 0.f);
      }
      hh[gr][kt] = mk_hi(ha);
    }
  }

  // agg = H@W2 + 12*b2
  f32x4 cg[4][4];
#pragma unroll
  for (int gr = 0; gr < 4; ++gr)
#pragma unroll
    for (int ct = 0; ct < 4; ++ct) cg[gr][ct] = bias4(12.f * b2[16 * ct + m]);
  stage_mm(WH, WL, segW2, 0, hh, l, cg);

  // u1: a-part (bf16 A, straight loads), then agg-part
  f32x4 cu[4][4];
#pragma unroll
  for (int gr = 0; gr < 4; ++gr)
#pragma unroll
    for (int ct = 0; ct < 4; ++ct) cu[gr][ct] = bias4(ub1[16 * ct + m]);
  {
    s16x8 arh[4][2];
#pragma unroll
    for (int gr = 0; gr < 4; ++gr)
#pragma unroll
      for (int kt = 0; kt < 2; ++kt)
        arh[gr][kt] = *(const s16x8*)(A + (size_t)nat[gr] * 64 + kt * 32 + g * 8);
    stage_mm(WH, WL, segU1, 0, arh, l, cu);
  }
  {
    s16x8 qh[4][2];
    trans_frags(sl, m, g, cg, qh);
    stage_mm(WH, WL, segU1, 2, qh, l, cu);
  }
#pragma unroll
  for (int gr = 0; gr < 4; ++gr)
#pragma unroll
    for (int ct = 0; ct < 4; ++ct)
#pragma unroll
      for (int r = 0; r < 4; ++r) cu[gr][ct][r] = fmaxf(cu[gr][ct][r], 0.f);

  // upd = u1@U2 + ub2
  f32x4 cd[4][4];
#pragma unroll
  for (int gr = 0; gr < 4; ++gr)
#pragma unroll
    for (int ct = 0; ct < 4; ++ct) cd[gr][ct] = bias4(ub2[16 * ct + m]);
  {
    s16x8 uh[4][2];
    trans_frags(sl, m, g, cu, uh);
    stage_mm(WH, WL, segU2, 0, uh, l, cd);
  }

  // a' = relu(a + upd): transpose (bf16 slab), residual re-read (bf16,
  // L2-hot), store (bf16 in-place | f32 raw), fragments for next stages.
  s16x8 anh[4][2];
#pragma unroll
  for (int h = 0; h < 2; ++h) {
    put_half_bf(sl, m, g, cd, h);
#pragma unroll
    for (int gr = 0; gr < 4; ++gr) {
      float v[8];
      get_half_f32(sl, m, g, gr, v);
      uint4 au = *(const uint4*)(A + (size_t)nat[gr] * 64 + 32 * h + 8 * g);
      float av[8] = {
        bf2f((u16)(au.x & 0xffff)), bf2f((u16)(au.x >> 16)),
        bf2f((u16)(au.y & 0xffff)), bf2f((u16)(au.y >> 16)),
        bf2f((u16)(au.z & 0xffff)), bf2f((u16)(au.z >> 16)),
        bf2f((u16)(au.w & 0xffff)), bf2f((u16)(au.w >> 16))};
#pragma unroll
      for (int i = 0; i < 8; ++i) v[i] = fmaxf(v[i] + av[i], 0.f);
      if constexpr (HAS_FX) {
        if (ok[gr]) {
          float* p = RawOut + (size_t)nat[gr] * 64 + 32 * h + 8 * g;
          *(float4*)p = make_float4(v[0], v[1], v[2], v[3]);
          *(float4*)(p + 4) = make_float4(v[4], v[5], v[6], v[7]);
        }
      } else {
        if (ok[gr]) pack_store8(A + (size_t)nat[gr] * 64 + 32 * h + 8 * g, v);
      }
      if constexpr (HAS_NEXT || HAS_FX) anh[gr][h] = mk_hi(v);
    }
  }

  if constexpr (HAS_NEXT) {
    // s_next (bf16, in-place over S)
    f32x4 cs[4][4];
#pragma unroll
    for (int gr = 0; gr < 4; ++gr)
#pragma unroll
      for (int ct = 0; ct < 4; ++ct) cs[gr][ct] = bias4(bn[16 * ct + m]);
    stage_mm(WH, WL, segWn, 0, anh, l, cs);
    trans_store_bf(sl, m, g, cs, S, nat, ok);

    // t_next (bf16, ping-pong buffer)
    f32x4 cT[4][4];
#pragma unroll
    for (int gr = 0; gr < 4; ++gr)
#pragma unroll
      for (int ct = 0; ct < 4; ++ct) cT[gr][ct] = bias4(0.f);
    stage_mm(WH, WL, segWn, 2, anh, l, cT);
    trans_store_bf(sl, m, g, cT, Tout, nat, ok);
  }

  if constexpr (HAS_FX) {
    // af = relu(raw@FX1+fb1)@FX2+fb2, hidden 128 in two 64-col rounds
    f32x4 cf[4][4];
#pragma unroll
    for (int gr = 0; gr < 4; ++gr)
#pragma unroll
      for (int ct = 0; ct < 4; ++ct) cf[gr][ct] = bias4(fb2[16 * ct + m]);

#pragma unroll
    for (int hr = 0; hr < 2; ++hr) {
      f32x4 chh[4][4];
#pragma unroll
      for (int gr = 0; gr < 4; ++gr)
#pragma unroll
        for (int ct = 0; ct < 4; ++ct)
          chh[gr][ct] = bias4(fb1[16 * (4 * hr + ct) + m]);
#pragma unroll
      for (int ct = 0; ct < 4; ++ct)
#pragma unroll
        for (int kt = 0; kt < 2; ++kt) {
          s16x8 bh, bl; ldB(WH, WL, 79872, kt, 4 * hr + ct, 8, l, bh, bl);
#pragma unroll
          for (int gr = 0; gr < 4; ++gr)
            chh[gr][ct] = mf2(anh[gr][kt], bh, bl, chh[gr][ct]);
        }
#pragma unroll
      for (int gr = 0; gr < 4; ++gr)
#pragma unroll
        for (int ct = 0; ct < 4; ++ct)
#pragma unroll
          for (int r = 0; r < 4; ++r) chh[gr][ct][r] = fmaxf(chh[gr][ct][r], 0.f);

      s16x8 hfh[4][2];
      trans_frags(sl, m, g, chh, hfh);
      stage_mm(WH, WL, 88064, 2 * hr, hfh, l, cf);
    }

    // AF store + props partials in the same A-layout pass
    float pp[4][4];
#pragma unroll
    for (int gr = 0; gr < 4; ++gr)
#pragma unroll
      for (int p = 0; p < 4; ++p) pp[gr][p] = 0.f;
#pragma unroll
    for (int h = 0; h < 2; ++h) {
      put_half_bf(sl, m, g, cf, h);
      f32x4 pw0[4], pw1[4];
#pragma unroll
      for (int p = 0; p < 4; ++p) {
        const float* q = PW + p * 64 + 32 * h + 8 * g;
        pw0[p] = *(const f32x4*)q;
        pw1[p] = *(const f32x4*)(q + 4);
      }
#pragma unroll
      for (int gr = 0; gr < 4; ++gr) {
        float v[8];
        get_half_f32(sl, m, g, gr, v);
        if (ok[gr]) {
          float* p = AF + (size_t)nat[gr] * 64 + 32 * h + 8 * g;
          *(float4*)p = make_float4(v[0], v[1], v[2], v[3]);
          *(float4*)(p + 4) = make_float4(v[4], v[5], v[6], v[7]);
        }
#pragma unroll
        for (int p = 0; p < 4; ++p)
#pragma unroll
          for (int i = 0; i < 4; ++i)
            pp[gr][p] += v[i] * pw0[p][i] + v[i + 4] * pw1[p][i];
      }
    }
    // reduce over g lanes (l^16, l^32), then lane (m,g) writes prop p=g
#pragma unroll
    for (int gr = 0; gr < 4; ++gr) {
      float r0 = pp[gr][0], r1 = pp[gr][1], r2 = pp[gr][2], r3 = pp[gr][3];
      r0 += __shfl_xor(r0, 16); r0 += __shfl_xor(r0, 32);
      r1 += __shfl_xor(r1, 16); r1 += __shfl_xor(r1, 32);
      r2 += __shfl_xor(r2, 16); r2 += __shfl_xor(r2, 32);
      r3 += __shfl_xor(r3, 16); r3 += __shfl_xor(r3, 32);
      float sel = (g == 0) ? r0 : (g == 1) ? r1 : (g == 2) ? r2 : r3;
      if (ok[gr]) PR[(size_t)nat[gr] * 4 + g] = sel + PB[g];
    }
  }
}

extern "C" void kernel_launch(void* const* d_in, const int* in_sizes, int n_in,
                              void* d_out, int out_size, void* d_ws, size_t ws_size,
                              hipStream_t stream) {
  const float* atom_fea = (const float*)d_in[0];
  const int*   nbr_idx  = (const int*)d_in[2];
  const float* ae_w   = (const float*)d_in[3];
  const float* ae_b   = (const float*)d_in[4];
  const float* msg_w1 = (const float*)d_in[7];
  const float* msg_b1 = (const float*)d_in[8];
  const float* msg_w2 = (const float*)d_in[9];
  const float* msg_b2 = (const float*)d_in[10];
  const float* upd_w1 = (const float*)d_in[11];
  const float* upd_b1 = (const float*)d_in[12];
  const float* upd_w2 = (const float*)d_in[13];
  const float* upd_b2 = (const float*)d_in[14];
  const float* fx_w1  = (const float*)d_in[15];
  const float* fx_b1  = (const float*)d_in[16];
  const float* fx_w2  = (const float*)d_in[17];
  const float* fx_b2  = (const float*)d_in[18];
  const float* prop_w = (const float*)d_in[19];
  const float* prop_b = (const float*)d_in[20];

  float* props   = (float*)d_out;
  float* af_reg  = props + (size_t)NA * 4;
  float* raw_reg = af_reg + (size_t)NA * 64;
  u16* Abf = (u16*)d_ws;               // [NA][64] bf16, in-place
  u16* S   = Abf + (size_t)NA * 64;    // [NA][64] bf16, in-place
  u16* T0  = S + (size_t)NA * 64;
  u16* T1  = T0 + (size_t)NA * 64;
  u16* WHp = T1 + (size_t)NA * 64;
  u16* WLp = WHp + 96256;

  k_prep<<<376, 256, 0, stream>>>(ae_w, msg_w1, msg_w2, upd_w1, upd_w2,
                                  fx_w1, fx_w2, WHp, WLp);

  int ngrid = (NA + 255) / 256;   // 1172
  k_embed_st<<<ngrid, 256, 0, stream>>>(atom_fea, WHp, WLp, ae_b, msg_b1,
                                        Abf, S, T0);

  const int base0 = 6144, base1 = 6144 + 24576, base2 = 6144 + 2 * 24576;

  // layer 0: A,S in-place; T0 -> T1
  k_dense<1, 0><<<ngrid, 256, 0, stream>>>(
      Abf, S, T0, nbr_idx, WHp, WLp,
      base0 + 8192, base0 + 12288, base0 + 20480, base1,
      msg_b2, upd_b1, upd_b2, msg_b1 + 64,
      fx_b1, fx_b2, prop_w, prop_b,
      T1, nullptr, nullptr, nullptr);

  // layer 1: A,S in-place; T1 -> T0
  k_dense<1, 0><<<ngrid, 256, 0, stream>>>(
      Abf, S, T1, nbr_idx, WHp, WLp,
      base1 + 8192, base1 + 12288, base1 + 20480, base2,
      msg_b2 + 64, upd_b1 + 64, upd_b2 + 64, msg_b1 + 128,
      fx_b1, fx_b2, prop_w, prop_b,
      T0, nullptr, nullptr, nullptr);

  // layer 2 + fx: raw -> raw_reg (f32), af -> af_reg, props -> d_out
  k_dense<0, 1><<<ngrid, 256, 0, stream>>>(
      Abf, S, T0, nbr_idx, WHp, WLp,
      base2 + 8192, base2 + 12288, base2 + 20480, 0,
      msg_b2 + 128, upd_b1 + 128, upd_b2 + 128, msg_b1,
      fx_b1, fx_b2, prop_w, prop_b,
      T1, raw_reg, af_reg, props);
}